// Round 11
// baseline (740.269 us; speedup 1.0000x reference)
//
#include <hip/hip_runtime.h>
#include <hip/hip_bf16.h>
#include <hip/hip_fp16.h>

#define N_NODES 50000
#define N_EDGES 1600000
#define IN_H 256
#define NHEAD 4
#define EDGE_H 64
#define N_ET 8

// ---- ws layout (word offsets), total 16,317,040 words = 65.3 MB ----
// counts8  int[8][50000]   @ 0         (zeroed; XCD-local copies, q=blk&7)
// cursor8  int[8][50000]   @ 400000    (zeroed)
// denom8   f32[8][200000]  @ 800000    (zeroed; XCD-local denom copies)
// hlmax    u32[4]          @ 2400000   (zeroed)
// hemax    u32[4]          @ 2400008
// flag     int[1]          @ 2400012   (zero region ends @ 2400064)
// hl       f32[200000]     @ 2400064
// hr       f32[200000]     @ 2600064
// offsets  int[50001]      @ 2800064
// off8     int[8][50000]   @ 2850112
// node_tot int[50000]      @ 3250112
// blk_sum  int[256]        @ 3300112
// blk_base int[256]        @ 3300368
// he       f32[32]         @ 3300624
// Wt       bf16[32768]     @ 3300656   (16384 words)
// p_by_e   int[3200000]    @ 3317040   (8B/edge: fp16 p0..3, by edge id)
// denom    f32[200000]     @ 6517040   (summed denominators)
// rec      int[6400000]    @ 6717040   (16B/edge: fp16 p0..3, s, pad)
// h        bf16[6400000]   @ 13117040  (3200000 words)

typedef __attribute__((ext_vector_type(8))) short bf16x8v;
typedef __attribute__((ext_vector_type(4))) float f32x4;

__device__ __forceinline__ float ldT(const float* p) { return *p; }
__device__ __forceinline__ float ldT(const __hip_bfloat16* p) { return __bfloat162float(*p); }
__device__ __forceinline__ void stT(float* p, float v) { *p = v; }
__device__ __forceinline__ void stT(__hip_bfloat16* p, float v) { *p = __float2bfloat16(v); }

__device__ __forceinline__ short f2bs(float f) {
    __hip_bfloat16 b = __float2bfloat16(f);
    return (short)__builtin_bit_cast(unsigned short, b);
}
__device__ __forceinline__ float bs2f(short s) {
    return __uint_as_float(((unsigned)(unsigned short)s) << 16);
}

__device__ __forceinline__ unsigned enc_f32(float f) {
    unsigned u = __float_as_uint(f);
    return (u & 0x80000000u) ? ~u : (u | 0x80000000u);
}
__device__ __forceinline__ float dec_f32(unsigned u) {
    return __uint_as_float((u & 0x80000000u) ? (u & 0x7fffffffu) : ~u);
}
__device__ __forceinline__ float lrelu(float v) { return v > 0.f ? v : 0.2f * v; }

__device__ __forceinline__ unsigned pack_h2(float a, float b) {
    unsigned lo = (unsigned)__half_as_ushort(__float2half(a));
    unsigned hi = (unsigned)__half_as_ushort(__float2half(b));
    return lo | (hi << 16);
}
__device__ __forceinline__ float2 unpack_h2(int w) {
    __half2 h = __builtin_bit_cast(__half2, w);
    return __half22float2(h);
}

// dtype detector: fp32 N(0,1) words have exp-field in [64,160]; bf16-packed
// words don't. DEVICE-side sniffing only (in_sizes are element counts).
__global__ void k_detect(const unsigned* __restrict__ xw, int* __restrict__ flag) {
    int lane = threadIdx.x;   // 64 threads
    int cnt = 0;
    for (int i = lane; i < 1024; i += 64) {
        unsigned e = (xw[i] >> 23) & 255u;
        if (e >= 64u && e <= 160u) cnt++;
    }
    for (int off = 32; off; off >>= 1) cnt += __shfl_xor(cnt, off);
    if (lane == 0) *flag = (cnt > 512) ? 1 : 0;   // 1 = fp32, 0 = bf16
}

// b0: W[256][128] -> Wt[128][256] bf16 (B^T layout for MFMA).
// b1..8: edge-type projection for type (b-1): he[ty][head] + hemax.
template<typename T, int EXPECT>
__global__ __launch_bounds__(256) void k_setup(
        const void* __restrict__ Wv, const void* __restrict__ embv,
        const void* __restrict__ Wev, const void* __restrict__ aev,
        __hip_bfloat16* __restrict__ Wt, float* __restrict__ h_e,
        unsigned* __restrict__ hemax, const int* __restrict__ flag) {
    if (*flag != EXPECT) return;
    const T* W   = (const T*)Wv;
    const T* emb = (const T*)embv;
    const T* We  = (const T*)Wev;
    const T* ae  = (const T*)aev;
    if (blockIdx.x == 0) {
        for (int i = threadIdx.x; i < 128 * 256; i += 256) {
            int c = i >> 8, k = i & 255;
            Wt[i] = __float2bfloat16(ldT(W + k * 128 + c));
        }
        return;
    }
    int ty = blockIdx.x - 1;
    int t = threadIdx.x, lane = t & 63;
    float acc = 0.f;
    for (int k = 0; k < EDGE_H; ++k)
        acc += ldT(emb + ty * EDGE_H + k) * ldT(We + k * 256 + t);
    float v = ldT(ae + t) * acc;
    for (int off = 32; off; off >>= 1) v += __shfl_xor(v, off);
    if (lane == 0) {
        h_e[ty * NHEAD + (t >> 6)] = v;
        atomicMax(&hemax[t >> 6], enc_f32(v));
    }
}

// h = x @ W via mfma_f32_16x16x32_bf16. 4 waves/block; 12500 waves.
// Prologue: folded per-target edge counts into XCD-LOCAL counts8[blk&7]
// (R8: single-copy atomics cost ~50MB cross-XCD HBM traffic).
// Epilogue: hl/hr from in-register h (quarter-lane butterfly).
template<typename T, int EXPECT>
__global__ __launch_bounds__(256) void k_proj(const void* __restrict__ xv,
        const __hip_bfloat16* __restrict__ Wt, __hip_bfloat16* __restrict__ h,
        float* __restrict__ hl, float* __restrict__ hr,
        const void* __restrict__ alv, const void* __restrict__ arv,
        const int* __restrict__ edge, int* __restrict__ counts8,
        const int* __restrict__ flag) {
    if (*flag != EXPECT) return;
    {   // folded k_count, XCD-local copy (same block->edge map as k_build)
        int q = blockIdx.x & 7;
        int base = blockIdx.x * 1024;
        int lim = min(base + 1024, N_EDGES);
        int* cnt = counts8 + q * 50000;
        for (int i = base + threadIdx.x; i < lim; i += 256)
            atomicAdd(&cnt[edge[N_EDGES + i]], 1);
    }
    const T* x  = (const T*)xv;
    const T* al = (const T*)alv;
    const T* ar = (const T*)arv;
    int wid = threadIdx.x >> 6, lane = threadIdx.x & 63;
    int rg = blockIdx.x * 2 + (wid >> 1);
    if (rg >= 3125) return;                 // no barriers below: safe early-exit
    int toff = (wid & 1) * 4;               // col-half: t-tiles toff..toff+3
    int r0 = rg * 16;
    int r = lane & 15;
    int kb = (lane >> 4) * 8;
    const T* xrow = x + (size_t)(r0 + r) * IN_H;
    f32x4 z = {0.f, 0.f, 0.f, 0.f};
    f32x4 acc[4];
#pragma unroll
    for (int t = 0; t < 4; ++t) acc[t] = z;
#pragma unroll
    for (int kk = 0; kk < 8; ++kk) {
        int k0 = kk * 32 + kb;
        bf16x8v a;
        if constexpr (sizeof(T) == 4) {
            float4 lo = *(const float4*)(xrow + k0);
            float4 hi = *(const float4*)(xrow + k0 + 4);
            a[0] = f2bs(lo.x); a[1] = f2bs(lo.y); a[2] = f2bs(lo.z); a[3] = f2bs(lo.w);
            a[4] = f2bs(hi.x); a[5] = f2bs(hi.y); a[6] = f2bs(hi.z); a[7] = f2bs(hi.w);
        } else {
            a = *(const bf16x8v*)(xrow + k0);
        }
#pragma unroll
        for (int t = 0; t < 4; ++t) {
            bf16x8v b = *(const bf16x8v*)(Wt + ((toff + t) * 16 + r) * 256 + k0);
            acc[t] = __builtin_amdgcn_mfma_f32_16x16x32_bf16(a, b, acc[t], 0, 0, 0);
        }
    }
    float alc[4], arc[4];
#pragma unroll
    for (int t = 0; t < 4; ++t) {
        alc[t] = ldT(al + (toff + t) * 16 + r);
        arc[t] = ldT(ar + (toff + t) * 16 + r);
    }
    int ob = (lane >> 4) * 4;               // this quarter's row offset
    float pl[2][4] = {{0,0,0,0},{0,0,0,0}}, pr[2][4] = {{0,0,0,0},{0,0,0,0}};
#pragma unroll
    for (int t = 0; t < 4; ++t) {
        int col = (toff + t) * 16 + r;
#pragma unroll
        for (int g = 0; g < 4; ++g) {
            float v = acc[t][g];
            if (v != v) v = 0.f;            // reference: where(isnan(h), 0)
            h[(size_t)(r0 + ob + g) * 128 + col] = __float2bfloat16(v);
            pl[t >> 1][g] += alc[t] * v;
            pr[t >> 1][g] += arc[t] * v;
        }
    }
#pragma unroll
    for (int hh = 0; hh < 2; ++hh)
#pragma unroll
        for (int g = 0; g < 4; ++g) {
            float vl = pl[hh][g], vr = pr[hh][g];
#pragma unroll
            for (int off = 8; off; off >>= 1) {
                vl += __shfl_xor(vl, off);
                vr += __shfl_xor(vr, off);
            }
            if (r == 0) {
                int node = r0 + ob + g;
                hl[node * 4 + (toff >> 1) + hh] = vl;
                hr[node * 4 + (toff >> 1) + hh] = vr;
            }
        }
}

// ---- 3-phase multi-block scan (R9: 1-block scan was 502us) ----

// A: per-node totals over 8 copies + per-block sums. Also folds the hl
// per-head maxima (wave shfl-max + <=3136 atomicMax, measured-safe volume).
__global__ __launch_bounds__(256) void k_scanA(
        const int* __restrict__ counts8, int* __restrict__ node_tot,
        int* __restrict__ blk_sum, const float* __restrict__ hl,
        unsigned* __restrict__ hlmax) {
    int n = blockIdx.x * 256 + threadIdx.x;
    int tot = 0;
    const float NEG = -3.4e38f;
    float4 ml = {NEG, NEG, NEG, NEG};
    if (n < N_NODES) {
#pragma unroll
        for (int q = 0; q < 8; ++q) tot += counts8[q * 50000 + n];
        node_tot[n] = tot;
        ml = *(const float4*)(hl + n * 4);
    }
    __shared__ int red[256];
    red[threadIdx.x] = tot;
    __syncthreads();
    for (int off = 128; off; off >>= 1) {
        if (threadIdx.x < off) red[threadIdx.x] += red[threadIdx.x + off];
        __syncthreads();
    }
    if (threadIdx.x == 0) blk_sum[blockIdx.x] = red[0];
#pragma unroll
    for (int off = 32; off; off >>= 1) {
        ml.x = fmaxf(ml.x, __shfl_xor(ml.x, off));
        ml.y = fmaxf(ml.y, __shfl_xor(ml.y, off));
        ml.z = fmaxf(ml.z, __shfl_xor(ml.z, off));
        ml.w = fmaxf(ml.w, __shfl_xor(ml.w, off));
    }
    if ((threadIdx.x & 63) == 0) {
        atomicMax(&hlmax[0], enc_f32(ml.x)); atomicMax(&hlmax[1], enc_f32(ml.y));
        atomicMax(&hlmax[2], enc_f32(ml.z)); atomicMax(&hlmax[3], enc_f32(ml.w));
    }
}

// B: exclusive scan of 196 block sums. 1 block.
__global__ __launch_bounds__(256) void k_scanB(
        const int* __restrict__ blk_sum, int* __restrict__ blk_base,
        int* __restrict__ offsets) {
    __shared__ int ps[256];
    int t = threadIdx.x;
    int v = (t < 196) ? blk_sum[t] : 0;
    ps[t] = v;
    __syncthreads();
    for (int off = 1; off < 256; off <<= 1) {
        int u = (t >= off) ? ps[t - off] : 0;
        __syncthreads();
        ps[t] += u;
        __syncthreads();
    }
    if (t < 196) blk_base[t] = ps[t] - v;   // exclusive
    if (t == 255) offsets[N_NODES] = ps[255];
}

// C: block-local exclusive scan of node_tot + blk_base -> offsets[n];
// then per-copy bases off8[q][n]. 196 blocks, fully parallel.
__global__ __launch_bounds__(256) void k_scanC(
        const int* __restrict__ counts8, const int* __restrict__ node_tot,
        const int* __restrict__ blk_base, int* __restrict__ offsets,
        int* __restrict__ off8) {
    __shared__ int ps[256];
    int t = threadIdx.x;
    int n = blockIdx.x * 256 + t;
    int v = (n < N_NODES) ? node_tot[n] : 0;
    ps[t] = v;
    __syncthreads();
    for (int off = 1; off < 256; off <<= 1) {
        int u = (t >= off) ? ps[t - off] : 0;
        __syncthreads();
        ps[t] += u;
        __syncthreads();
    }
    if (n < N_NODES) {
        int base = blk_base[blockIdx.x] + ps[t] - v;
        offsets[n] = base;
#pragma unroll
        for (int q = 0; q < 8; ++q) {
            off8[q * 50000 + n] = base;
            base += counts8[q * 50000 + n];
        }
    }
}

// CSR build: per edge one 16B record {fp16 p0..p3, s, pad} + linear
// p_by_e[e] write + XCD-local denominator atomics denom8[q][t][h].
// Per-target shift M_t,h = lrelu(hlmax_h + hr[t][h] + hemax_h) (R8-verified).
// SAME block->edge map as k_proj's count fold (1024 edges, q=blk&7).
__global__ __launch_bounds__(256) void k_build(
        const int* __restrict__ edge, const int* __restrict__ off8,
        int* __restrict__ cursor8, float* __restrict__ denom8,
        const float* __restrict__ hl, const float* __restrict__ hr,
        const float* __restrict__ he,
        const unsigned* __restrict__ hlmax, const unsigned* __restrict__ hemax,
        int* __restrict__ rec, int* __restrict__ p_by_e) {
    float G0 = dec_f32(hlmax[0]) + dec_f32(hemax[0]);
    float G1 = dec_f32(hlmax[1]) + dec_f32(hemax[1]);
    float G2 = dec_f32(hlmax[2]) + dec_f32(hemax[2]);
    float G3 = dec_f32(hlmax[3]) + dec_f32(hemax[3]);
    int q = blockIdx.x & 7;
    const int* offq = off8 + q * 50000;
    int* curq = cursor8 + q * 50000;
    float* denq = denom8 + q * 200000;
    int base = blockIdx.x * 1024;
    int lim = min(base + 1024, N_EDGES);
    for (int e = base + threadIdx.x; e < lim; e += 256) {
        int s = edge[e], t = edge[N_EDGES + e], ty = edge[2 * N_EDGES + e];
        int pos = offq[t] + atomicAdd(&curq[t], 1);
        float4 a = *(const float4*)(hl + s * 4);
        float4 b = *(const float4*)(hr + t * 4);
        float4 c = *(const float4*)(he + ty * 4);
        float p0 = __expf(lrelu(a.x + b.x + c.x) - lrelu(G0 + b.x));
        float p1 = __expf(lrelu(a.y + b.y + c.y) - lrelu(G1 + b.y));
        float p2 = __expf(lrelu(a.z + b.z + c.z) - lrelu(G2 + b.z));
        float p3 = __expf(lrelu(a.w + b.w + c.w) - lrelu(G3 + b.w));
        int4 w;
        w.x = (int)pack_h2(p0, p1);
        w.y = (int)pack_h2(p2, p3);
        w.z = s;
        w.w = 0;
        *(int4*)(rec + (size_t)pos * 4) = w;
        *(int2*)(p_by_e + (size_t)e * 2) = make_int2(w.x, w.y);  // linear
        atomicAdd(&denq[t * 4 + 0], p0);
        atomicAdd(&denq[t * 4 + 1], p1);
        atomicAdd(&denq[t * 4 + 2], p2);
        atomicAdd(&denq[t * 4 + 3], p3);
    }
}

// sum the 8 XCD-local denominator copies -> denom[t][h]
__global__ __launch_bounds__(256) void k_sumden(
        const float* __restrict__ denom8, float* __restrict__ denom) {
    int n = blockIdx.x * 256 + threadIdx.x;
    if (n >= N_NODES) return;
    float4 d = {0.f, 0.f, 0.f, 0.f};
#pragma unroll
    for (int q = 0; q < 8; ++q) {
        float4 v = *(const float4*)(denom8 + q * 200000 + n * 4);
        d.x += v.x; d.y += v.y; d.z += v.z; d.w += v.w;
    }
    *(float4*)(denom + n * 4) = d;
}

// attn output, fully linear: read p_by_e[e] + trg[e] sequentially,
// gather denom[t] (800KB, L2-resident), write attn_out[e*4] coalesced.
// (R10: attn as CSR-ordered scatter inside k_agg cost ~25MB write ampl.)
template<typename OUTT, int EXPECT>
__global__ __launch_bounds__(256) void k_attn(
        const int* __restrict__ p_by_e, const int* __restrict__ edge,
        const float* __restrict__ denom, void* __restrict__ outv,
        const int* __restrict__ flag) {
    if (*flag != EXPECT) return;
    int e = blockIdx.x * 256 + threadIdx.x;   // 6250*256 == N_EDGES
    int t = edge[N_EDGES + e];
    float4 d = *(const float4*)(denom + t * 4);
    int2 w = *(const int2*)(p_by_e + (size_t)e * 2);
    float2 f01 = unpack_h2(w.x);
    float2 f23 = unpack_h2(w.y);
    OUTT* attn_out = (OUTT*)outv + (size_t)N_NODES * 128;
    stT(&attn_out[(size_t)e * 4 + 0], f01.x / (d.x + 1e-16f));
    stT(&attn_out[(size_t)e * 4 + 1], f01.y / (d.y + 1e-16f));
    stT(&attn_out[(size_t)e * 4 + 2], f23.x / (d.z + 1e-16f));
    stT(&attn_out[(size_t)e * 4 + 3], f23.y / (d.w + 1e-16f));
}

// one wave per node, 4 edges/iter: quarter-wave owns an edge, 16 lanes own
// 8 dims each (16B h load), cross-quarter shfl reduce at end. Denominators
// precomputed (no pass 1, no attn writes, no divergent branches).
template<typename OUTT, int EXPECT>
__global__ __launch_bounds__(256) void k_agg(
        const int* __restrict__ rec, const int* __restrict__ offsets,
        const float* __restrict__ denom, const __hip_bfloat16* __restrict__ h,
        void* __restrict__ outv, const int* __restrict__ flag) {
    if (*flag != EXPECT) return;
    OUTT* out = (OUTT*)outv;
    int node = (blockIdx.x << 2) + (threadIdx.x >> 6);
    if (node >= N_NODES) return;
    int lane = threadIdx.x & 63;
    int beg = offsets[node], end = offsets[node + 1];

    float4 dn = *(const float4*)(denom + node * 4);
    float inv0 = 1.f / (dn.x + 1e-16f), inv1 = 1.f / (dn.y + 1e-16f);
    float inv2 = 1.f / (dn.z + 1e-16f), inv3 = 1.f / (dn.w + 1e-16f);

    int sub = lane >> 4;          // edge slot within group of 4
    int l16 = lane & 15;          // dim group: flat dims l16*8 .. +8
    int hd  = l16 >> 2;           // head of my dims
    float invd = hd == 0 ? inv0 : hd == 1 ? inv1 : hd == 2 ? inv2 : inv3;

    float acc[8] = {0.f, 0.f, 0.f, 0.f, 0.f, 0.f, 0.f, 0.f};
    for (int jg = beg; jg < end; jg += 4) {
        int j = jg + sub;
        bool valid = j < end;
        int jc = valid ? j : end - 1;
        const int* rp = rec + (size_t)jc * 4;
        int pw = (hd < 2) ? rp[0] : rp[1];
        int s = rp[2];
        float2 f = unpack_h2(pw);
        float phd = (hd & 1) ? f.y : f.x;
        float wgt = valid ? phd * invd : 0.f;
        bf16x8v hv = *(const bf16x8v*)(h + (size_t)s * 128 + l16 * 8);
#pragma unroll
        for (int i = 0; i < 8; ++i) acc[i] += bs2f(hv[i]) * wgt;
    }
#pragma unroll
    for (int i = 0; i < 8; ++i) {
        acc[i] += __shfl_xor(acc[i], 16);
        acc[i] += __shfl_xor(acc[i], 32);
    }
    if (sub == 0) {
#pragma unroll
        for (int i = 0; i < 8; ++i)
            stT(&out[(size_t)node * 128 + l16 * 8 + i], acc[i]);
    }
}

extern "C" void kernel_launch(void* const* d_in, const int* in_sizes, int n_in,
                              void* d_out, int out_size, void* d_ws, size_t ws_size,
                              hipStream_t stream) {
    const int* edge = (const int*)d_in[0];
    const void* x   = d_in[1];
    const void* emb = d_in[2];
    const void* W   = d_in[3];
    const void* We  = d_in[4];
    const void* al  = d_in[5];
    const void* ar  = d_in[6];
    const void* ae  = d_in[7];

    float* ws = (float*)d_ws;
    int* counts8    = (int*)ws;                        // 400000
    int* cursor8    = counts8 + 400000;                // 400000
    float* denom8   = ws + 800000;                     // 1600000
    unsigned* hlmax = (unsigned*)(ws + 2400000);       // 4
    unsigned* hemax = (unsigned*)(ws + 2400008);       // 4
    int* flag       = (int*)ws + 2400012;              // 1
    float* hl       = ws + 2400064;                    // 200000
    float* hr       = ws + 2600064;                    // 200000
    int* offsets    = (int*)ws + 2800064;              // 50001
    int* off8       = (int*)ws + 2850112;              // 400000
    int* node_tot   = (int*)ws + 3250112;              // 50000
    int* blk_sum    = (int*)ws + 3300112;              // 256
    int* blk_base   = (int*)ws + 3300368;              // 256
    float* he       = ws + 3300624;                    // 32
    __hip_bfloat16* Wt = (__hip_bfloat16*)(ws + 3300656);  // 32768 bf16
    int* p_by_e     = (int*)ws + 3317040;              // 3200000
    float* denom    = ws + 6517040;                    // 200000
    int* rec        = (int*)ws + 6717040;              // 6400000 (16B/edge)
    __hip_bfloat16* h = (__hip_bfloat16*)(ws + 13117040);  // 6400000 bf16
    // total 16,317,040 words = 65.3 MB

    hipMemsetAsync(ws, 0, (size_t)2400064 * 4, stream); // counts8+cursor8+denom8+maxima+flag

    k_detect<<<1, 64, 0, stream>>>((const unsigned*)x, flag);

    k_setup<float, 1><<<1 + N_ET, 256, 0, stream>>>(W, emb, We, ae, Wt, he,
                                                    hemax, flag);
    k_setup<__hip_bfloat16, 0><<<1 + N_ET, 256, 0, stream>>>(W, emb, We, ae, Wt,
                                                             he, hemax, flag);

    k_proj<float, 1><<<1563, 256, 0, stream>>>(x, Wt, h, hl, hr, al, ar,
                                               edge, counts8, flag);
    k_proj<__hip_bfloat16, 0><<<1563, 256, 0, stream>>>(x, Wt, h, hl, hr,
                                                        al, ar, edge, counts8, flag);

    k_scanA<<<196, 256, 0, stream>>>(counts8, node_tot, blk_sum, hl, hlmax);
    k_scanB<<<1, 256, 0, stream>>>(blk_sum, blk_base, offsets);
    k_scanC<<<196, 256, 0, stream>>>(counts8, node_tot, blk_base, offsets, off8);
    k_build<<<1563, 256, 0, stream>>>(edge, off8, cursor8, denom8, hl, hr, he,
                                      hlmax, hemax, rec, p_by_e);
    k_sumden<<<196, 256, 0, stream>>>(denom8, denom);

    k_attn<float, 1><<<6250, 256, 0, stream>>>(p_by_e, edge, denom, d_out, flag);
    k_attn<__hip_bfloat16, 0><<<6250, 256, 0, stream>>>(p_by_e, edge, denom,
                                                        d_out, flag);

    k_agg<float, 1><<<12500, 256, 0, stream>>>(rec, offsets, denom, h, d_out, flag);
    k_agg<__hip_bfloat16, 0><<<12500, 256, 0, stream>>>(rec, offsets, denom, h,
                                                        d_out, flag);
}

// Round 12
// 454.546 us; speedup vs baseline: 1.6286x; 1.6286x over previous
//
#include <hip/hip_runtime.h>
#include <hip/hip_bf16.h>
#include <hip/hip_fp16.h>

#define N_NODES 50000
#define N_EDGES 1600000
#define IN_H 256
#define NHEAD 4
#define EDGE_H 64
#define N_ET 8

// ---- ws layout (word offsets), total 14,717,040 words = 58.9 MB ----
// counts8  int[8][50000]   @ 0         (zeroed; XCD-local copies, q=blk&7)
// cursor8  int[8][50000]   @ 400000    (zeroed)
// hlmax    u32[4]          @ 800000    (zeroed)
// hemax    u32[4]          @ 800008
// flag     int[1]          @ 800012    (zero region ends @ 800064)
// hl       f32[200000]     @ 800064
// hr       f32[200000]     @ 1000064
// offsets  int[50001]      @ 1200064
// off8     int[8][50000]   @ 1250112
// node_tot int[50000]      @ 1650112
// blk_sum  int[256]        @ 1700112
// blk_base int[256]        @ 1700368
// he       f32[32]         @ 1700624
// Wt       bf16[32768]     @ 1700656   (16384 words)
// denom    f32[200000]     @ 1717040   (written by k_agg pass 1)
// p_by_e   int[3200000]    @ 1917040   (8B/edge: fp16 p0..3, by edge id)
// rec      int[6400000]    @ 5117040   (16B/edge: fp16 p0..3, s, pad)
// h        bf16[6400000]   @ 11517040  (3200000 words)

typedef __attribute__((ext_vector_type(8))) short bf16x8v;
typedef __attribute__((ext_vector_type(4))) float f32x4;

__device__ __forceinline__ float ldT(const float* p) { return *p; }
__device__ __forceinline__ float ldT(const __hip_bfloat16* p) { return __bfloat162float(*p); }
__device__ __forceinline__ void stT(float* p, float v) { *p = v; }
__device__ __forceinline__ void stT(__hip_bfloat16* p, float v) { *p = __float2bfloat16(v); }

__device__ __forceinline__ short f2bs(float f) {
    __hip_bfloat16 b = __float2bfloat16(f);
    return (short)__builtin_bit_cast(unsigned short, b);
}
__device__ __forceinline__ float bs2f(short s) {
    return __uint_as_float(((unsigned)(unsigned short)s) << 16);
}

__device__ __forceinline__ unsigned enc_f32(float f) {
    unsigned u = __float_as_uint(f);
    return (u & 0x80000000u) ? ~u : (u | 0x80000000u);
}
__device__ __forceinline__ float dec_f32(unsigned u) {
    return __uint_as_float((u & 0x80000000u) ? (u & 0x7fffffffu) : ~u);
}
__device__ __forceinline__ float lrelu(float v) { return v > 0.f ? v : 0.2f * v; }

__device__ __forceinline__ unsigned pack_h2(float a, float b) {
    unsigned lo = (unsigned)__half_as_ushort(__float2half(a));
    unsigned hi = (unsigned)__half_as_ushort(__float2half(b));
    return lo | (hi << 16);
}
__device__ __forceinline__ float2 unpack_h2(int w) {
    __half2 h = __builtin_bit_cast(__half2, w);
    return __half22float2(h);
}

// dtype detector: fp32 N(0,1) words have exp-field in [64,160]; bf16-packed
// words don't. DEVICE-side sniffing only (in_sizes are element counts).
__global__ void k_detect(const unsigned* __restrict__ xw, int* __restrict__ flag) {
    int lane = threadIdx.x;   // 64 threads
    int cnt = 0;
    for (int i = lane; i < 1024; i += 64) {
        unsigned e = (xw[i] >> 23) & 255u;
        if (e >= 64u && e <= 160u) cnt++;
    }
    for (int off = 32; off; off >>= 1) cnt += __shfl_xor(cnt, off);
    if (lane == 0) *flag = (cnt > 512) ? 1 : 0;   // 1 = fp32, 0 = bf16
}

// b0: W[256][128] -> Wt[128][256] bf16 (B^T layout for MFMA).
// b1..8: edge-type projection for type (b-1): he[ty][head] + hemax.
template<typename T, int EXPECT>
__global__ __launch_bounds__(256) void k_setup(
        const void* __restrict__ Wv, const void* __restrict__ embv,
        const void* __restrict__ Wev, const void* __restrict__ aev,
        __hip_bfloat16* __restrict__ Wt, float* __restrict__ h_e,
        unsigned* __restrict__ hemax, const int* __restrict__ flag) {
    if (*flag != EXPECT) return;
    const T* W   = (const T*)Wv;
    const T* emb = (const T*)embv;
    const T* We  = (const T*)Wev;
    const T* ae  = (const T*)aev;
    if (blockIdx.x == 0) {
        for (int i = threadIdx.x; i < 128 * 256; i += 256) {
            int c = i >> 8, k = i & 255;
            Wt[i] = __float2bfloat16(ldT(W + k * 128 + c));
        }
        return;
    }
    int ty = blockIdx.x - 1;
    int t = threadIdx.x, lane = t & 63;
    float acc = 0.f;
    for (int k = 0; k < EDGE_H; ++k)
        acc += ldT(emb + ty * EDGE_H + k) * ldT(We + k * 256 + t);
    float v = ldT(ae + t) * acc;
    for (int off = 32; off; off >>= 1) v += __shfl_xor(v, off);
    if (lane == 0) {
        h_e[ty * NHEAD + (t >> 6)] = v;
        atomicMax(&hemax[t >> 6], enc_f32(v));
    }
}

// h = x @ W via mfma_f32_16x16x32_bf16. 4 waves/block; 12500 waves.
// Prologue: folded per-target edge counts into XCD-LOCAL counts8[blk&7]
// (R8: single-copy atomics cost ~50MB cross-XCD HBM traffic; R11: >1
// atomic/edge to hot lines is atomic-throughput-bound — never do 4/edge).
// Epilogue: hl/hr from in-register h (quarter-lane butterfly).
template<typename T, int EXPECT>
__global__ __launch_bounds__(256) void k_proj(const void* __restrict__ xv,
        const __hip_bfloat16* __restrict__ Wt, __hip_bfloat16* __restrict__ h,
        float* __restrict__ hl, float* __restrict__ hr,
        const void* __restrict__ alv, const void* __restrict__ arv,
        const int* __restrict__ edge, int* __restrict__ counts8,
        const int* __restrict__ flag) {
    if (*flag != EXPECT) return;
    {   // folded k_count, XCD-local copy (same block->edge map as k_build)
        int q = blockIdx.x & 7;
        int base = blockIdx.x * 1024;
        int lim = min(base + 1024, N_EDGES);
        int* cnt = counts8 + q * 50000;
        for (int i = base + threadIdx.x; i < lim; i += 256)
            atomicAdd(&cnt[edge[N_EDGES + i]], 1);
    }
    const T* x  = (const T*)xv;
    const T* al = (const T*)alv;
    const T* ar = (const T*)arv;
    int wid = threadIdx.x >> 6, lane = threadIdx.x & 63;
    int rg = blockIdx.x * 2 + (wid >> 1);
    if (rg >= 3125) return;                 // no barriers below: safe early-exit
    int toff = (wid & 1) * 4;               // col-half: t-tiles toff..toff+3
    int r0 = rg * 16;
    int r = lane & 15;
    int kb = (lane >> 4) * 8;
    const T* xrow = x + (size_t)(r0 + r) * IN_H;
    f32x4 z = {0.f, 0.f, 0.f, 0.f};
    f32x4 acc[4];
#pragma unroll
    for (int t = 0; t < 4; ++t) acc[t] = z;
#pragma unroll
    for (int kk = 0; kk < 8; ++kk) {
        int k0 = kk * 32 + kb;
        bf16x8v a;
        if constexpr (sizeof(T) == 4) {
            float4 lo = *(const float4*)(xrow + k0);
            float4 hi = *(const float4*)(xrow + k0 + 4);
            a[0] = f2bs(lo.x); a[1] = f2bs(lo.y); a[2] = f2bs(lo.z); a[3] = f2bs(lo.w);
            a[4] = f2bs(hi.x); a[5] = f2bs(hi.y); a[6] = f2bs(hi.z); a[7] = f2bs(hi.w);
        } else {
            a = *(const bf16x8v*)(xrow + k0);
        }
#pragma unroll
        for (int t = 0; t < 4; ++t) {
            bf16x8v b = *(const bf16x8v*)(Wt + ((toff + t) * 16 + r) * 256 + k0);
            acc[t] = __builtin_amdgcn_mfma_f32_16x16x32_bf16(a, b, acc[t], 0, 0, 0);
        }
    }
    float alc[4], arc[4];
#pragma unroll
    for (int t = 0; t < 4; ++t) {
        alc[t] = ldT(al + (toff + t) * 16 + r);
        arc[t] = ldT(ar + (toff + t) * 16 + r);
    }
    int ob = (lane >> 4) * 4;               // this quarter's row offset
    float pl[2][4] = {{0,0,0,0},{0,0,0,0}}, pr[2][4] = {{0,0,0,0},{0,0,0,0}};
#pragma unroll
    for (int t = 0; t < 4; ++t) {
        int col = (toff + t) * 16 + r;
#pragma unroll
        for (int g = 0; g < 4; ++g) {
            float v = acc[t][g];
            if (v != v) v = 0.f;            // reference: where(isnan(h), 0)
            h[(size_t)(r0 + ob + g) * 128 + col] = __float2bfloat16(v);
            pl[t >> 1][g] += alc[t] * v;
            pr[t >> 1][g] += arc[t] * v;
        }
    }
#pragma unroll
    for (int hh = 0; hh < 2; ++hh)
#pragma unroll
        for (int g = 0; g < 4; ++g) {
            float vl = pl[hh][g], vr = pr[hh][g];
#pragma unroll
            for (int off = 8; off; off >>= 1) {
                vl += __shfl_xor(vl, off);
                vr += __shfl_xor(vr, off);
            }
            if (r == 0) {
                int node = r0 + ob + g;
                hl[node * 4 + (toff >> 1) + hh] = vl;
                hr[node * 4 + (toff >> 1) + hh] = vr;
            }
        }
}

// ---- 3-phase multi-block scan (R9: 1-block scan was 502us) ----

// A: per-node totals over 8 copies + per-block sums. Also folds the hl
// per-head maxima (wave shfl-max + <=3136 atomicMax, measured-safe volume).
__global__ __launch_bounds__(256) void k_scanA(
        const int* __restrict__ counts8, int* __restrict__ node_tot,
        int* __restrict__ blk_sum, const float* __restrict__ hl,
        unsigned* __restrict__ hlmax) {
    int n = blockIdx.x * 256 + threadIdx.x;
    int tot = 0;
    const float NEG = -3.4e38f;
    float4 ml = {NEG, NEG, NEG, NEG};
    if (n < N_NODES) {
#pragma unroll
        for (int q = 0; q < 8; ++q) tot += counts8[q * 50000 + n];
        node_tot[n] = tot;
        ml = *(const float4*)(hl + n * 4);
    }
    __shared__ int red[256];
    red[threadIdx.x] = tot;
    __syncthreads();
    for (int off = 128; off; off >>= 1) {
        if (threadIdx.x < off) red[threadIdx.x] += red[threadIdx.x + off];
        __syncthreads();
    }
    if (threadIdx.x == 0) blk_sum[blockIdx.x] = red[0];
#pragma unroll
    for (int off = 32; off; off >>= 1) {
        ml.x = fmaxf(ml.x, __shfl_xor(ml.x, off));
        ml.y = fmaxf(ml.y, __shfl_xor(ml.y, off));
        ml.z = fmaxf(ml.z, __shfl_xor(ml.z, off));
        ml.w = fmaxf(ml.w, __shfl_xor(ml.w, off));
    }
    if ((threadIdx.x & 63) == 0) {
        atomicMax(&hlmax[0], enc_f32(ml.x)); atomicMax(&hlmax[1], enc_f32(ml.y));
        atomicMax(&hlmax[2], enc_f32(ml.z)); atomicMax(&hlmax[3], enc_f32(ml.w));
    }
}

// B: exclusive scan of 196 block sums. 1 block.
__global__ __launch_bounds__(256) void k_scanB(
        const int* __restrict__ blk_sum, int* __restrict__ blk_base,
        int* __restrict__ offsets) {
    __shared__ int ps[256];
    int t = threadIdx.x;
    int v = (t < 196) ? blk_sum[t] : 0;
    ps[t] = v;
    __syncthreads();
    for (int off = 1; off < 256; off <<= 1) {
        int u = (t >= off) ? ps[t - off] : 0;
        __syncthreads();
        ps[t] += u;
        __syncthreads();
    }
    if (t < 196) blk_base[t] = ps[t] - v;   // exclusive
    if (t == 255) offsets[N_NODES] = ps[255];
}

// C: block-local exclusive scan of node_tot + blk_base -> offsets[n];
// then per-copy bases off8[q][n]. 196 blocks, fully parallel.
__global__ __launch_bounds__(256) void k_scanC(
        const int* __restrict__ counts8, const int* __restrict__ node_tot,
        const int* __restrict__ blk_base, int* __restrict__ offsets,
        int* __restrict__ off8) {
    __shared__ int ps[256];
    int t = threadIdx.x;
    int n = blockIdx.x * 256 + t;
    int v = (n < N_NODES) ? node_tot[n] : 0;
    ps[t] = v;
    __syncthreads();
    for (int off = 1; off < 256; off <<= 1) {
        int u = (t >= off) ? ps[t - off] : 0;
        __syncthreads();
        ps[t] += u;
        __syncthreads();
    }
    if (n < N_NODES) {
        int base = blk_base[blockIdx.x] + ps[t] - v;
        offsets[n] = base;
#pragma unroll
        for (int q = 0; q < 8; ++q) {
            off8[q * 50000 + n] = base;
            base += counts8[q * 50000 + n];
        }
    }
}

// CSR build: per edge one 16B record {fp16 p0..p3, s, pad} + linear
// p_by_e[e] write. NO denom atomics (R11: 4 atomics/edge to hot lines =
// atomic-throughput-bound, +300us). Per-target shift M_t,h =
// lrelu(hlmax_h + hr[t][h] + hemax_h) (R8-verified exact).
// SAME block->edge map as k_proj's count fold (1024 edges, q=blk&7).
__global__ __launch_bounds__(256) void k_build(
        const int* __restrict__ edge, const int* __restrict__ off8,
        int* __restrict__ cursor8,
        const float* __restrict__ hl, const float* __restrict__ hr,
        const float* __restrict__ he,
        const unsigned* __restrict__ hlmax, const unsigned* __restrict__ hemax,
        int* __restrict__ rec, int* __restrict__ p_by_e) {
    float G0 = dec_f32(hlmax[0]) + dec_f32(hemax[0]);
    float G1 = dec_f32(hlmax[1]) + dec_f32(hemax[1]);
    float G2 = dec_f32(hlmax[2]) + dec_f32(hemax[2]);
    float G3 = dec_f32(hlmax[3]) + dec_f32(hemax[3]);
    int q = blockIdx.x & 7;
    const int* offq = off8 + q * 50000;
    int* curq = cursor8 + q * 50000;
    int base = blockIdx.x * 1024;
    int lim = min(base + 1024, N_EDGES);
    for (int e = base + threadIdx.x; e < lim; e += 256) {
        int s = edge[e], t = edge[N_EDGES + e], ty = edge[2 * N_EDGES + e];
        int pos = offq[t] + atomicAdd(&curq[t], 1);
        float4 a = *(const float4*)(hl + s * 4);
        float4 b = *(const float4*)(hr + t * 4);
        float4 c = *(const float4*)(he + ty * 4);
        float p0 = __expf(lrelu(a.x + b.x + c.x) - lrelu(G0 + b.x));
        float p1 = __expf(lrelu(a.y + b.y + c.y) - lrelu(G1 + b.y));
        float p2 = __expf(lrelu(a.z + b.z + c.z) - lrelu(G2 + b.z));
        float p3 = __expf(lrelu(a.w + b.w + c.w) - lrelu(G3 + b.w));
        int4 w;
        w.x = (int)pack_h2(p0, p1);
        w.y = (int)pack_h2(p2, p3);
        w.z = s;
        w.w = 0;
        *(int4*)(rec + (size_t)pos * 4) = w;
        *(int2*)(p_by_e + (size_t)e * 2) = make_int2(w.x, w.y);  // linear
    }
}

// one wave per node. pass1: lane-parallel denom over rec (coalesced, and
// rec stays L2-hot for pass 2); lane 0 stores denom[node] for k_attn.
// pass2: 4 edges/iter — quarter-wave owns an edge, 16 lanes own 8 dims
// each (16B h load), cross-quarter shfl reduce at end. No attn writes
// (moved to linear k_attn; R10: CSR-scatter attn cost ~25MB write ampl).
template<typename OUTT, int EXPECT>
__global__ __launch_bounds__(256) void k_agg(
        const int* __restrict__ rec, const int* __restrict__ offsets,
        float* __restrict__ denom, const __hip_bfloat16* __restrict__ h,
        void* __restrict__ outv, const int* __restrict__ flag) {
    if (*flag != EXPECT) return;
    OUTT* out = (OUTT*)outv;
    int node = (blockIdx.x << 2) + (threadIdx.x >> 6);
    if (node >= N_NODES) return;
    int lane = threadIdx.x & 63;
    int beg = offsets[node], end = offsets[node + 1];

    // pass 1: denominators
    float d0 = 0.f, d1 = 0.f, d2 = 0.f, d3 = 0.f;
    for (int j = beg + lane; j < end; j += 64) {
        int2 w = *(const int2*)(rec + (size_t)j * 4);
        float2 f01 = unpack_h2(w.x);
        float2 f23 = unpack_h2(w.y);
        d0 += f01.x; d1 += f01.y; d2 += f23.x; d3 += f23.y;
    }
#pragma unroll
    for (int off = 32; off; off >>= 1) {
        d0 += __shfl_xor(d0, off); d1 += __shfl_xor(d1, off);
        d2 += __shfl_xor(d2, off); d3 += __shfl_xor(d3, off);
    }
    if (lane == 0) *(float4*)(denom + node * 4) = make_float4(d0, d1, d2, d3);
    float inv0 = 1.f / (d0 + 1e-16f), inv1 = 1.f / (d1 + 1e-16f);
    float inv2 = 1.f / (d2 + 1e-16f), inv3 = 1.f / (d3 + 1e-16f);

    int sub = lane >> 4;          // edge slot within group of 4
    int l16 = lane & 15;          // dim group: flat dims l16*8 .. +8
    int hd  = l16 >> 2;           // head of my dims
    float invd = hd == 0 ? inv0 : hd == 1 ? inv1 : hd == 2 ? inv2 : inv3;

    float acc[8] = {0.f, 0.f, 0.f, 0.f, 0.f, 0.f, 0.f, 0.f};
    for (int jg = beg; jg < end; jg += 4) {
        int j = jg + sub;
        bool valid = j < end;
        int jc = valid ? j : end - 1;
        const int* rp = rec + (size_t)jc * 4;
        int pw = (hd < 2) ? rp[0] : rp[1];
        int s = rp[2];
        float2 f = unpack_h2(pw);
        float phd = (hd & 1) ? f.y : f.x;
        float wgt = valid ? phd * invd : 0.f;
        bf16x8v hv = *(const bf16x8v*)(h + (size_t)s * 128 + l16 * 8);
#pragma unroll
        for (int i = 0; i < 8; ++i) acc[i] += bs2f(hv[i]) * wgt;
    }
#pragma unroll
    for (int i = 0; i < 8; ++i) {
        acc[i] += __shfl_xor(acc[i], 16);
        acc[i] += __shfl_xor(acc[i], 32);
    }
    if (sub == 0) {
#pragma unroll
        for (int i = 0; i < 8; ++i)
            stT(&out[(size_t)node * 128 + l16 * 8 + i], acc[i]);
    }
}

// attn output, fully linear: read p_by_e[e] + trg[e] sequentially,
// gather denom[t] (800KB, L2/L3-resident), write attn_out[e*4] coalesced.
template<typename OUTT, int EXPECT>
__global__ __launch_bounds__(256) void k_attn(
        const int* __restrict__ p_by_e, const int* __restrict__ edge,
        const float* __restrict__ denom, void* __restrict__ outv,
        const int* __restrict__ flag) {
    if (*flag != EXPECT) return;
    int e = blockIdx.x * 256 + threadIdx.x;   // 6250*256 == N_EDGES
    int t = edge[N_EDGES + e];
    float4 d = *(const float4*)(denom + t * 4);
    int2 w = *(const int2*)(p_by_e + (size_t)e * 2);
    float2 f01 = unpack_h2(w.x);
    float2 f23 = unpack_h2(w.y);
    OUTT* attn_out = (OUTT*)outv + (size_t)N_NODES * 128;
    stT(&attn_out[(size_t)e * 4 + 0], f01.x / (d.x + 1e-16f));
    stT(&attn_out[(size_t)e * 4 + 1], f01.y / (d.y + 1e-16f));
    stT(&attn_out[(size_t)e * 4 + 2], f23.x / (d.z + 1e-16f));
    stT(&attn_out[(size_t)e * 4 + 3], f23.y / (d.w + 1e-16f));
}

extern "C" void kernel_launch(void* const* d_in, const int* in_sizes, int n_in,
                              void* d_out, int out_size, void* d_ws, size_t ws_size,
                              hipStream_t stream) {
    const int* edge = (const int*)d_in[0];
    const void* x   = d_in[1];
    const void* emb = d_in[2];
    const void* W   = d_in[3];
    const void* We  = d_in[4];
    const void* al  = d_in[5];
    const void* ar  = d_in[6];
    const void* ae  = d_in[7];

    float* ws = (float*)d_ws;
    int* counts8    = (int*)ws;                        // 400000
    int* cursor8    = counts8 + 400000;                // 400000
    unsigned* hlmax = (unsigned*)(ws + 800000);        // 4
    unsigned* hemax = (unsigned*)(ws + 800008);        // 4
    int* flag       = (int*)ws + 800012;               // 1
    float* hl       = ws + 800064;                     // 200000
    float* hr       = ws + 1000064;                    // 200000
    int* offsets    = (int*)ws + 1200064;              // 50001
    int* off8       = (int*)ws + 1250112;              // 400000
    int* node_tot   = (int*)ws + 1650112;              // 50000
    int* blk_sum    = (int*)ws + 1700112;              // 256
    int* blk_base   = (int*)ws + 1700368;              // 256
    float* he       = ws + 1700624;                    // 32
    __hip_bfloat16* Wt = (__hip_bfloat16*)(ws + 1700656);  // 32768 bf16
    float* denom    = ws + 1717040;                    // 200000
    int* p_by_e     = (int*)ws + 1917040;              // 3200000
    int* rec        = (int*)ws + 5117040;              // 6400000 (16B/edge)
    __hip_bfloat16* h = (__hip_bfloat16*)(ws + 11517040);  // 6400000 bf16
    // total 14,717,040 words = 58.9 MB

    hipMemsetAsync(ws, 0, (size_t)800064 * 4, stream); // counts8+cursor8+maxima+flag

    k_detect<<<1, 64, 0, stream>>>((const unsigned*)x, flag);

    k_setup<float, 1><<<1 + N_ET, 256, 0, stream>>>(W, emb, We, ae, Wt, he,
                                                    hemax, flag);
    k_setup<__hip_bfloat16, 0><<<1 + N_ET, 256, 0, stream>>>(W, emb, We, ae, Wt,
                                                             he, hemax, flag);

    k_proj<float, 1><<<1563, 256, 0, stream>>>(x, Wt, h, hl, hr, al, ar,
                                               edge, counts8, flag);
    k_proj<__hip_bfloat16, 0><<<1563, 256, 0, stream>>>(x, Wt, h, hl, hr,
                                                        al, ar, edge, counts8, flag);

    k_scanA<<<196, 256, 0, stream>>>(counts8, node_tot, blk_sum, hl, hlmax);
    k_scanB<<<1, 256, 0, stream>>>(blk_sum, blk_base, offsets);
    k_scanC<<<196, 256, 0, stream>>>(counts8, node_tot, blk_base, offsets, off8);
    k_build<<<1563, 256, 0, stream>>>(edge, off8, cursor8, hl, hr, he,
                                      hlmax, hemax, rec, p_by_e);

    k_agg<float, 1><<<12500, 256, 0, stream>>>(rec, offsets, denom, h, d_out, flag);
    k_agg<__hip_bfloat16, 0><<<12500, 256, 0, stream>>>(rec, offsets, denom, h,
                                                        d_out, flag);

    k_attn<float, 1><<<6250, 256, 0, stream>>>(p_by_e, edge, denom, d_out, flag);
    k_attn<__hip_bfloat16, 0><<<6250, 256, 0, stream>>>(p_by_e, edge, denom,
                                                        d_out, flag);
}

// Round 13
// 446.077 us; speedup vs baseline: 1.6595x; 1.0190x over previous
//
#include <hip/hip_runtime.h>
#include <hip/hip_bf16.h>
#include <hip/hip_fp16.h>

#define N_NODES 50000
#define N_EDGES 1600000
#define IN_H 256
#define NHEAD 4
#define EDGE_H 64
#define N_ET 8

// ---- ws layout (word offsets), total 14,717,040 words = 58.9 MB ----
// counts8  int[8][50000]   @ 0         (zeroed; XCD-local copies, q=blk&7)
// cursor8  int[8][50000]   @ 400000    (zeroed)
// hlmax    u32[4]          @ 800000    (zeroed)
// hemax    u32[4]          @ 800008
// flag     int[1]          @ 800012    (zero region ends @ 800064)
// hl       f32[200000]     @ 800064
// hr       f32[200000]     @ 1000064
// offsets  int[50001]      @ 1200064
// off8     int[8][50000]   @ 1250112
// node_tot int[50000]      @ 1650112
// blk_sum  int[256]        @ 1700112
// blk_base int[256]        @ 1700368
// he       f32[32]         @ 1700624
// Wt       bf16[32768]     @ 1700656   (16384 words)
// denom    f32[200000]     @ 1717040   (written by k_agg pass 1)
// p_by_e   int[3200000]    @ 1917040   (8B/edge: fp16 p0..3, by edge id)
// rec      int[6400000]    @ 5117040   (16B/edge: fp16 p0..3, s, pad)
// h        bf16[6400000]   @ 11517040  (3200000 words)

typedef __attribute__((ext_vector_type(8))) short bf16x8v;
typedef __attribute__((ext_vector_type(4))) float f32x4;

__device__ __forceinline__ float ldT(const float* p) { return *p; }
__device__ __forceinline__ float ldT(const __hip_bfloat16* p) { return __bfloat162float(*p); }
__device__ __forceinline__ void stT(float* p, float v) { *p = v; }
__device__ __forceinline__ void stT(__hip_bfloat16* p, float v) { *p = __float2bfloat16(v); }

__device__ __forceinline__ short f2bs(float f) {
    __hip_bfloat16 b = __float2bfloat16(f);
    return (short)__builtin_bit_cast(unsigned short, b);
}
__device__ __forceinline__ float bs2f(short s) {
    return __uint_as_float(((unsigned)(unsigned short)s) << 16);
}

__device__ __forceinline__ unsigned enc_f32(float f) {
    unsigned u = __float_as_uint(f);
    return (u & 0x80000000u) ? ~u : (u | 0x80000000u);
}
__device__ __forceinline__ float dec_f32(unsigned u) {
    return __uint_as_float((u & 0x80000000u) ? (u & 0x7fffffffu) : ~u);
}
__device__ __forceinline__ float lrelu(float v) { return v > 0.f ? v : 0.2f * v; }

__device__ __forceinline__ unsigned pack_h2(float a, float b) {
    unsigned lo = (unsigned)__half_as_ushort(__float2half(a));
    unsigned hi = (unsigned)__half_as_ushort(__float2half(b));
    return lo | (hi << 16);
}
__device__ __forceinline__ float2 unpack_h2(int w) {
    __half2 h = __builtin_bit_cast(__half2, w);
    return __half22float2(h);
}

// dtype detector: fp32 N(0,1) words have exp-field in [64,160]; bf16-packed
// words don't. DEVICE-side sniffing only (in_sizes are element counts).
__global__ void k_detect(const unsigned* __restrict__ xw, int* __restrict__ flag) {
    int lane = threadIdx.x;   // 64 threads
    int cnt = 0;
    for (int i = lane; i < 1024; i += 64) {
        unsigned e = (xw[i] >> 23) & 255u;
        if (e >= 64u && e <= 160u) cnt++;
    }
    for (int off = 32; off; off >>= 1) cnt += __shfl_xor(cnt, off);
    if (lane == 0) *flag = (cnt > 512) ? 1 : 0;   // 1 = fp32, 0 = bf16
}

// b0: W[256][128] -> Wt[128][256] bf16 (B^T layout for MFMA).
// b1..8: edge-type projection for type (b-1): he[ty][head] + hemax.
template<typename T, int EXPECT>
__global__ __launch_bounds__(256) void k_setup(
        const void* __restrict__ Wv, const void* __restrict__ embv,
        const void* __restrict__ Wev, const void* __restrict__ aev,
        __hip_bfloat16* __restrict__ Wt, float* __restrict__ h_e,
        unsigned* __restrict__ hemax, const int* __restrict__ flag) {
    if (*flag != EXPECT) return;
    const T* W   = (const T*)Wv;
    const T* emb = (const T*)embv;
    const T* We  = (const T*)Wev;
    const T* ae  = (const T*)aev;
    if (blockIdx.x == 0) {
        for (int i = threadIdx.x; i < 128 * 256; i += 256) {
            int c = i >> 8, k = i & 255;
            Wt[i] = __float2bfloat16(ldT(W + k * 128 + c));
        }
        return;
    }
    int ty = blockIdx.x - 1;
    int t = threadIdx.x, lane = t & 63;
    float acc = 0.f;
    for (int k = 0; k < EDGE_H; ++k)
        acc += ldT(emb + ty * EDGE_H + k) * ldT(We + k * 256 + t);
    float v = ldT(ae + t) * acc;
    for (int off = 32; off; off >>= 1) v += __shfl_xor(v, off);
    if (lane == 0) {
        h_e[ty * NHEAD + (t >> 6)] = v;
        atomicMax(&hemax[t >> 6], enc_f32(v));
    }
}

// h = x @ W via mfma_f32_16x16x32_bf16. 4 waves/block; 12500 waves.
// Prologue: folded per-target edge counts into XCD-LOCAL counts8[blk&7]
// (R8: single-copy atomics cost ~50MB cross-XCD HBM traffic; R11: >1
// atomic/edge to hot lines is atomic-throughput-bound — never do 4/edge).
// Epilogue: hl/hr from in-register h (quarter-lane butterfly).
template<typename T, int EXPECT>
__global__ __launch_bounds__(256) void k_proj(const void* __restrict__ xv,
        const __hip_bfloat16* __restrict__ Wt, __hip_bfloat16* __restrict__ h,
        float* __restrict__ hl, float* __restrict__ hr,
        const void* __restrict__ alv, const void* __restrict__ arv,
        const int* __restrict__ edge, int* __restrict__ counts8,
        const int* __restrict__ flag) {
    if (*flag != EXPECT) return;
    {   // folded k_count, XCD-local copy (q matches k_build's mapping)
        int q = blockIdx.x & 7;
        int base = blockIdx.x * 1024;
        int lim = min(base + 1024, N_EDGES);
        int* cnt = counts8 + q * 50000;
        for (int i = base + threadIdx.x; i < lim; i += 256)
            atomicAdd(&cnt[edge[N_EDGES + i]], 1);
    }
    const T* x  = (const T*)xv;
    const T* al = (const T*)alv;
    const T* ar = (const T*)arv;
    int wid = threadIdx.x >> 6, lane = threadIdx.x & 63;
    int rg = blockIdx.x * 2 + (wid >> 1);
    if (rg >= 3125) return;                 // no barriers below: safe early-exit
    int toff = (wid & 1) * 4;               // col-half: t-tiles toff..toff+3
    int r0 = rg * 16;
    int r = lane & 15;
    int kb = (lane >> 4) * 8;
    const T* xrow = x + (size_t)(r0 + r) * IN_H;
    f32x4 z = {0.f, 0.f, 0.f, 0.f};
    f32x4 acc[4];
#pragma unroll
    for (int t = 0; t < 4; ++t) acc[t] = z;
#pragma unroll
    for (int kk = 0; kk < 8; ++kk) {
        int k0 = kk * 32 + kb;
        bf16x8v a;
        if constexpr (sizeof(T) == 4) {
            float4 lo = *(const float4*)(xrow + k0);
            float4 hi = *(const float4*)(xrow + k0 + 4);
            a[0] = f2bs(lo.x); a[1] = f2bs(lo.y); a[2] = f2bs(lo.z); a[3] = f2bs(lo.w);
            a[4] = f2bs(hi.x); a[5] = f2bs(hi.y); a[6] = f2bs(hi.z); a[7] = f2bs(hi.w);
        } else {
            a = *(const bf16x8v*)(xrow + k0);
        }
#pragma unroll
        for (int t = 0; t < 4; ++t) {
            bf16x8v b = *(const bf16x8v*)(Wt + ((toff + t) * 16 + r) * 256 + k0);
            acc[t] = __builtin_amdgcn_mfma_f32_16x16x32_bf16(a, b, acc[t], 0, 0, 0);
        }
    }
    float alc[4], arc[4];
#pragma unroll
    for (int t = 0; t < 4; ++t) {
        alc[t] = ldT(al + (toff + t) * 16 + r);
        arc[t] = ldT(ar + (toff + t) * 16 + r);
    }
    int ob = (lane >> 4) * 4;               // this quarter's row offset
    float pl[2][4] = {{0,0,0,0},{0,0,0,0}}, pr[2][4] = {{0,0,0,0},{0,0,0,0}};
#pragma unroll
    for (int t = 0; t < 4; ++t) {
        int col = (toff + t) * 16 + r;
#pragma unroll
        for (int g = 0; g < 4; ++g) {
            float v = acc[t][g];
            if (v != v) v = 0.f;            // reference: where(isnan(h), 0)
            h[(size_t)(r0 + ob + g) * 128 + col] = __float2bfloat16(v);
            pl[t >> 1][g] += alc[t] * v;
            pr[t >> 1][g] += arc[t] * v;
        }
    }
#pragma unroll
    for (int hh = 0; hh < 2; ++hh)
#pragma unroll
        for (int g = 0; g < 4; ++g) {
            float vl = pl[hh][g], vr = pr[hh][g];
#pragma unroll
            for (int off = 8; off; off >>= 1) {
                vl += __shfl_xor(vl, off);
                vr += __shfl_xor(vr, off);
            }
            if (r == 0) {
                int node = r0 + ob + g;
                hl[node * 4 + (toff >> 1) + hh] = vl;
                hr[node * 4 + (toff >> 1) + hh] = vr;
            }
        }
}

// ---- 3-phase multi-block scan (R9: 1-block scan was 502us) ----

// A: per-node totals over 8 copies + per-block sums. Also folds the hl
// per-head maxima (wave shfl-max + <=3136 atomicMax, measured-safe volume).
__global__ __launch_bounds__(256) void k_scanA(
        const int* __restrict__ counts8, int* __restrict__ node_tot,
        int* __restrict__ blk_sum, const float* __restrict__ hl,
        unsigned* __restrict__ hlmax) {
    int n = blockIdx.x * 256 + threadIdx.x;
    int tot = 0;
    const float NEG = -3.4e38f;
    float4 ml = {NEG, NEG, NEG, NEG};
    if (n < N_NODES) {
#pragma unroll
        for (int q = 0; q < 8; ++q) tot += counts8[q * 50000 + n];
        node_tot[n] = tot;
        ml = *(const float4*)(hl + n * 4);
    }
    __shared__ int red[256];
    red[threadIdx.x] = tot;
    __syncthreads();
    for (int off = 128; off; off >>= 1) {
        if (threadIdx.x < off) red[threadIdx.x] += red[threadIdx.x + off];
        __syncthreads();
    }
    if (threadIdx.x == 0) blk_sum[blockIdx.x] = red[0];
#pragma unroll
    for (int off = 32; off; off >>= 1) {
        ml.x = fmaxf(ml.x, __shfl_xor(ml.x, off));
        ml.y = fmaxf(ml.y, __shfl_xor(ml.y, off));
        ml.z = fmaxf(ml.z, __shfl_xor(ml.z, off));
        ml.w = fmaxf(ml.w, __shfl_xor(ml.w, off));
    }
    if ((threadIdx.x & 63) == 0) {
        atomicMax(&hlmax[0], enc_f32(ml.x)); atomicMax(&hlmax[1], enc_f32(ml.y));
        atomicMax(&hlmax[2], enc_f32(ml.z)); atomicMax(&hlmax[3], enc_f32(ml.w));
    }
}

// B: exclusive scan of 196 block sums. 1 block.
__global__ __launch_bounds__(256) void k_scanB(
        const int* __restrict__ blk_sum, int* __restrict__ blk_base,
        int* __restrict__ offsets) {
    __shared__ int ps[256];
    int t = threadIdx.x;
    int v = (t < 196) ? blk_sum[t] : 0;
    ps[t] = v;
    __syncthreads();
    for (int off = 1; off < 256; off <<= 1) {
        int u = (t >= off) ? ps[t - off] : 0;
        __syncthreads();
        ps[t] += u;
        __syncthreads();
    }
    if (t < 196) blk_base[t] = ps[t] - v;   // exclusive
    if (t == 255) offsets[N_NODES] = ps[255];
}

// C: block-local exclusive scan of node_tot + blk_base -> offsets[n];
// then per-copy bases off8[q][n]. 196 blocks, fully parallel.
__global__ __launch_bounds__(256) void k_scanC(
        const int* __restrict__ counts8, const int* __restrict__ node_tot,
        const int* __restrict__ blk_base, int* __restrict__ offsets,
        int* __restrict__ off8) {
    __shared__ int ps[256];
    int t = threadIdx.x;
    int n = blockIdx.x * 256 + t;
    int v = (n < N_NODES) ? node_tot[n] : 0;
    ps[t] = v;
    __syncthreads();
    for (int off = 1; off < 256; off <<= 1) {
        int u = (t >= off) ? ps[t - off] : 0;
        __syncthreads();
        ps[t] += u;
        __syncthreads();
    }
    if (n < N_NODES) {
        int base = blk_base[blockIdx.x] + ps[t] - v;
        offsets[n] = base;
#pragma unroll
        for (int q = 0; q < 8; ++q) {
            off8[q * 50000 + n] = base;
            base += counts8[q * 50000 + n];
        }
    }
}

// CSR build: per edge one 16B record {fp16 p0..p3, s, pad} + linear
// p_by_e[e] write. 1 edge/thread, 6250 blocks (R12 post-mortem: the
// 4-edges/thread loop serialized 4 dependent atomic->scatter chains per
// thread at 39% occupancy; R6's 1-edge/thread shape ran ~90us).
// q must match k_proj's counting copy: proj-block b = e/1024 used q=b&7,
// and this block covers e in [256*blk, ...), so q = (blk>>2)&7.
// Per-target shift M_t,h = lrelu(hlmax_h + hr[t][h] + hemax_h) (R8-exact).
__global__ __launch_bounds__(256) void k_build(
        const int* __restrict__ edge, const int* __restrict__ off8,
        int* __restrict__ cursor8,
        const float* __restrict__ hl, const float* __restrict__ hr,
        const float* __restrict__ he,
        const unsigned* __restrict__ hlmax, const unsigned* __restrict__ hemax,
        int* __restrict__ rec, int* __restrict__ p_by_e) {
    float G0 = dec_f32(hlmax[0]) + dec_f32(hemax[0]);
    float G1 = dec_f32(hlmax[1]) + dec_f32(hemax[1]);
    float G2 = dec_f32(hlmax[2]) + dec_f32(hemax[2]);
    float G3 = dec_f32(hlmax[3]) + dec_f32(hemax[3]);
    int q = (blockIdx.x >> 2) & 7;
    const int* offq = off8 + q * 50000;
    int* curq = cursor8 + q * 50000;
    int e = blockIdx.x * 256 + threadIdx.x;   // 6250*256 == N_EDGES exactly
    int s = edge[e], t = edge[N_EDGES + e], ty = edge[2 * N_EDGES + e];
    int pos = offq[t] + atomicAdd(&curq[t], 1);
    float4 a = *(const float4*)(hl + s * 4);
    float4 b = *(const float4*)(hr + t * 4);
    float4 c = *(const float4*)(he + ty * 4);
    float p0 = __expf(lrelu(a.x + b.x + c.x) - lrelu(G0 + b.x));
    float p1 = __expf(lrelu(a.y + b.y + c.y) - lrelu(G1 + b.y));
    float p2 = __expf(lrelu(a.z + b.z + c.z) - lrelu(G2 + b.z));
    float p3 = __expf(lrelu(a.w + b.w + c.w) - lrelu(G3 + b.w));
    int4 w;
    w.x = (int)pack_h2(p0, p1);
    w.y = (int)pack_h2(p2, p3);
    w.z = s;
    w.w = 0;
    *(int4*)(rec + (size_t)pos * 4) = w;
    *(int2*)(p_by_e + (size_t)e * 2) = make_int2(w.x, w.y);  // linear
}

// one wave per node. pass1: lane-parallel denom over rec (coalesced, and
// rec stays L2-hot for pass 2); lane 0 stores denom[node] for k_attn.
// pass2: 4 edges/iter — quarter-wave owns an edge, 16 lanes own 8 dims
// each (16B h load), cross-quarter shfl reduce at end. No attn writes.
// Node order is XCD-swizzled (bijective, m204 form) so each XCD's L2
// streams a contiguous rec region instead of an 8-way interleave.
template<typename OUTT, int EXPECT>
__global__ __launch_bounds__(256) void k_agg(
        const int* __restrict__ rec, const int* __restrict__ offsets,
        float* __restrict__ denom, const __hip_bfloat16* __restrict__ h,
        void* __restrict__ outv, const int* __restrict__ flag) {
    if (*flag != EXPECT) return;
    OUTT* out = (OUTT*)outv;
    // bijective XCD swizzle over 12500 blocks: q=12500/8=1562, r=4
    int xcd = blockIdx.x & 7, idx = blockIdx.x >> 3;
    int nq = 1562, nr = 4;
    int sb = (xcd < nr) ? xcd * (nq + 1) + idx : nr * (nq + 1) + (xcd - nr) * nq + idx;
    int node = (sb << 2) + (threadIdx.x >> 6);
    if (node >= N_NODES) return;
    int lane = threadIdx.x & 63;
    int beg = offsets[node], end = offsets[node + 1];

    // pass 1: denominators
    float d0 = 0.f, d1 = 0.f, d2 = 0.f, d3 = 0.f;
    for (int j = beg + lane; j < end; j += 64) {
        int2 w = *(const int2*)(rec + (size_t)j * 4);
        float2 f01 = unpack_h2(w.x);
        float2 f23 = unpack_h2(w.y);
        d0 += f01.x; d1 += f01.y; d2 += f23.x; d3 += f23.y;
    }
#pragma unroll
    for (int off = 32; off; off >>= 1) {
        d0 += __shfl_xor(d0, off); d1 += __shfl_xor(d1, off);
        d2 += __shfl_xor(d2, off); d3 += __shfl_xor(d3, off);
    }
    if (lane == 0) *(float4*)(denom + node * 4) = make_float4(d0, d1, d2, d3);
    float inv0 = 1.f / (d0 + 1e-16f), inv1 = 1.f / (d1 + 1e-16f);
    float inv2 = 1.f / (d2 + 1e-16f), inv3 = 1.f / (d3 + 1e-16f);

    int sub = lane >> 4;          // edge slot within group of 4
    int l16 = lane & 15;          // dim group: flat dims l16*8 .. +8
    int hd  = l16 >> 2;           // head of my dims
    float invd = hd == 0 ? inv0 : hd == 1 ? inv1 : hd == 2 ? inv2 : inv3;

    float acc[8] = {0.f, 0.f, 0.f, 0.f, 0.f, 0.f, 0.f, 0.f};
    for (int jg = beg; jg < end; jg += 4) {
        int j = jg + sub;
        bool valid = j < end;
        int jc = valid ? j : end - 1;
        const int* rp = rec + (size_t)jc * 4;
        int pw = (hd < 2) ? rp[0] : rp[1];
        int s = rp[2];
        float2 f = unpack_h2(pw);
        float phd = (hd & 1) ? f.y : f.x;
        float wgt = valid ? phd * invd : 0.f;
        bf16x8v hv = *(const bf16x8v*)(h + (size_t)s * 128 + l16 * 8);
#pragma unroll
        for (int i = 0; i < 8; ++i) acc[i] += bs2f(hv[i]) * wgt;
    }
#pragma unroll
    for (int i = 0; i < 8; ++i) {
        acc[i] += __shfl_xor(acc[i], 16);
        acc[i] += __shfl_xor(acc[i], 32);
    }
    if (sub == 0) {
#pragma unroll
        for (int i = 0; i < 8; ++i)
            stT(&out[(size_t)node * 128 + l16 * 8 + i], acc[i]);
    }
}

// attn output, fully linear: read p_by_e[e] + trg[e] sequentially,
// gather denom[t] (800KB, L2/L3-resident), write attn_out[e*4] coalesced.
template<typename OUTT, int EXPECT>
__global__ __launch_bounds__(256) void k_attn(
        const int* __restrict__ p_by_e, const int* __restrict__ edge,
        const float* __restrict__ denom, void* __restrict__ outv,
        const int* __restrict__ flag) {
    if (*flag != EXPECT) return;
    int e = blockIdx.x * 256 + threadIdx.x;   // 6250*256 == N_EDGES
    int t = edge[N_EDGES + e];
    float4 d = *(const float4*)(denom + t * 4);
    int2 w = *(const int2*)(p_by_e + (size_t)e * 2);
    float2 f01 = unpack_h2(w.x);
    float2 f23 = unpack_h2(w.y);
    OUTT* attn_out = (OUTT*)outv + (size_t)N_NODES * 128;
    stT(&attn_out[(size_t)e * 4 + 0], f01.x / (d.x + 1e-16f));
    stT(&attn_out[(size_t)e * 4 + 1], f01.y / (d.y + 1e-16f));
    stT(&attn_out[(size_t)e * 4 + 2], f23.x / (d.z + 1e-16f));
    stT(&attn_out[(size_t)e * 4 + 3], f23.y / (d.w + 1e-16f));
}

extern "C" void kernel_launch(void* const* d_in, const int* in_sizes, int n_in,
                              void* d_out, int out_size, void* d_ws, size_t ws_size,
                              hipStream_t stream) {
    const int* edge = (const int*)d_in[0];
    const void* x   = d_in[1];
    const void* emb = d_in[2];
    const void* W   = d_in[3];
    const void* We  = d_in[4];
    const void* al  = d_in[5];
    const void* ar  = d_in[6];
    const void* ae  = d_in[7];

    float* ws = (float*)d_ws;
    int* counts8    = (int*)ws;                        // 400000
    int* cursor8    = counts8 + 400000;                // 400000
    unsigned* hlmax = (unsigned*)(ws + 800000);        // 4
    unsigned* hemax = (unsigned*)(ws + 800008);        // 4
    int* flag       = (int*)ws + 800012;               // 1
    float* hl       = ws + 800064;                     // 200000
    float* hr       = ws + 1000064;                    // 200000
    int* offsets    = (int*)ws + 1200064;              // 50001
    int* off8       = (int*)ws + 1250112;              // 400000
    int* node_tot   = (int*)ws + 1650112;              // 50000
    int* blk_sum    = (int*)ws + 1700112;              // 256
    int* blk_base   = (int*)ws + 1700368;              // 256
    float* he       = ws + 1700624;                    // 32
    __hip_bfloat16* Wt = (__hip_bfloat16*)(ws + 1700656);  // 32768 bf16
    float* denom    = ws + 1717040;                    // 200000
    int* p_by_e     = (int*)ws + 1917040;              // 3200000
    int* rec        = (int*)ws + 5117040;              // 6400000 (16B/edge)
    __hip_bfloat16* h = (__hip_bfloat16*)(ws + 11517040);  // 6400000 bf16
    // total 14,717,040 words = 58.9 MB

    hipMemsetAsync(ws, 0, (size_t)800064 * 4, stream); // counts8+cursor8+maxima+flag

    k_detect<<<1, 64, 0, stream>>>((const unsigned*)x, flag);

    k_setup<float, 1><<<1 + N_ET, 256, 0, stream>>>(W, emb, We, ae, Wt, he,
                                                    hemax, flag);
    k_setup<__hip_bfloat16, 0><<<1 + N_ET, 256, 0, stream>>>(W, emb, We, ae, Wt,
                                                             he, hemax, flag);

    k_proj<float, 1><<<1563, 256, 0, stream>>>(x, Wt, h, hl, hr, al, ar,
                                               edge, counts8, flag);
    k_proj<__hip_bfloat16, 0><<<1563, 256, 0, stream>>>(x, Wt, h, hl, hr,
                                                        al, ar, edge, counts8, flag);

    k_scanA<<<196, 256, 0, stream>>>(counts8, node_tot, blk_sum, hl, hlmax);
    k_scanB<<<1, 256, 0, stream>>>(blk_sum, blk_base, offsets);
    k_scanC<<<196, 256, 0, stream>>>(counts8, node_tot, blk_base, offsets, off8);
    k_build<<<6250, 256, 0, stream>>>(edge, off8, cursor8, hl, hr, he,
                                      hlmax, hemax, rec, p_by_e);

    k_agg<float, 1><<<12500, 256, 0, stream>>>(rec, offsets, denom, h, d_out, flag);
    k_agg<__hip_bfloat16, 0><<<12500, 256, 0, stream>>>(rec, offsets, denom, h,
                                                        d_out, flag);

    k_attn<float, 1><<<6250, 256, 0, stream>>>(p_by_e, edge, denom, d_out, flag);
    k_attn<__hip_bfloat16, 0><<<6250, 256, 0, stream>>>(p_by_e, edge, denom,
                                                        d_out, flag);
}

// Round 14
// 434.115 us; speedup vs baseline: 1.7052x; 1.0276x over previous
//
#include <hip/hip_runtime.h>
#include <hip/hip_bf16.h>
#include <hip/hip_fp16.h>

#define N_NODES 50000
#define N_EDGES 1600000
#define IN_H 256
#define NHEAD 4
#define EDGE_H 64
#define N_ET 8

// ---- ws layout (word offsets), total 14,717,040 words = 58.9 MB ----
// counts8  int[8][50000]   @ 0         (zeroed; XCD-local copies)
// cursor8  int[8][50000]   @ 400000    (zeroed)
// hlmax    u32[4]          @ 800000    (zeroed)
// hemax    u32[4]          @ 800008
// flag     int[1]          @ 800012    (zero region ends @ 800064)
// hl       f32[200000]     @ 800064
// hr       f32[200000]     @ 1000064
// offsets  int[50001]      @ 1200064
// off8     int[8][50000]   @ 1250112
// node_tot int[50000]      @ 1650112
// blk_sum  int[256]        @ 1700112
// he       f32[32]         @ 1700624
// Wt       bf16[32768]     @ 1700656   (16384 words)
// denom    f32[200000]     @ 1717040   (written by k_agg pass 1)
// p_by_e   int[3200000]    @ 1917040   (8B/edge: fp16 p0..3, by edge id)
// rec      int[6400000]    @ 5117040   (16B/edge: fp16 p0..3, s, pad)
// h        bf16[6400000]   @ 11517040  (3200000 words)

typedef __attribute__((ext_vector_type(8))) short bf16x8v;
typedef __attribute__((ext_vector_type(4))) float f32x4;

__device__ __forceinline__ float ldT(const float* p) { return *p; }
__device__ __forceinline__ float ldT(const __hip_bfloat16* p) { return __bfloat162float(*p); }
__device__ __forceinline__ void stT(float* p, float v) { *p = v; }
__device__ __forceinline__ void stT(__hip_bfloat16* p, float v) { *p = __float2bfloat16(v); }

__device__ __forceinline__ short f2bs(float f) {
    __hip_bfloat16 b = __float2bfloat16(f);
    return (short)__builtin_bit_cast(unsigned short, b);
}
__device__ __forceinline__ float bs2f(short s) {
    return __uint_as_float(((unsigned)(unsigned short)s) << 16);
}

__device__ __forceinline__ unsigned enc_f32(float f) {
    unsigned u = __float_as_uint(f);
    return (u & 0x80000000u) ? ~u : (u | 0x80000000u);
}
__device__ __forceinline__ float dec_f32(unsigned u) {
    return __uint_as_float((u & 0x80000000u) ? (u & 0x7fffffffu) : ~u);
}
__device__ __forceinline__ float lrelu(float v) { return v > 0.f ? v : 0.2f * v; }

__device__ __forceinline__ unsigned pack_h2(float a, float b) {
    unsigned lo = (unsigned)__half_as_ushort(__float2half(a));
    unsigned hi = (unsigned)__half_as_ushort(__float2half(b));
    return lo | (hi << 16);
}
__device__ __forceinline__ float2 unpack_h2(int w) {
    __half2 h = __builtin_bit_cast(__half2, w);
    return __half22float2(h);
}

// dtype detector: fp32 N(0,1) words have exp-field in [64,160]; bf16-packed
// words don't. DEVICE-side sniffing only (in_sizes are element counts).
__global__ void k_detect(const unsigned* __restrict__ xw, int* __restrict__ flag) {
    int lane = threadIdx.x;   // 64 threads
    int cnt = 0;
    for (int i = lane; i < 1024; i += 64) {
        unsigned e = (xw[i] >> 23) & 255u;
        if (e >= 64u && e <= 160u) cnt++;
    }
    for (int off = 32; off; off >>= 1) cnt += __shfl_xor(cnt, off);
    if (lane == 0) *flag = (cnt > 512) ? 1 : 0;   // 1 = fp32, 0 = bf16
}

// b0: W[256][128] -> Wt[128][256] bf16. b1..8: edge-type projection.
template<typename T>
__device__ __forceinline__ void setup_body(const T* __restrict__ W,
        const T* __restrict__ emb, const T* __restrict__ We,
        const T* __restrict__ ae, __hip_bfloat16* __restrict__ Wt,
        float* __restrict__ h_e, unsigned* __restrict__ hemax) {
    if (blockIdx.x == 0) {
        for (int i = threadIdx.x; i < 128 * 256; i += 256) {
            int c = i >> 8, k = i & 255;
            Wt[i] = __float2bfloat16(ldT(W + k * 128 + c));
        }
        return;
    }
    int ty = blockIdx.x - 1;
    int t = threadIdx.x, lane = t & 63;
    float acc = 0.f;
    for (int k = 0; k < EDGE_H; ++k)
        acc += ldT(emb + ty * EDGE_H + k) * ldT(We + k * 256 + t);
    float v = ldT(ae + t) * acc;
    for (int off = 32; off; off >>= 1) v += __shfl_xor(v, off);
    if (lane == 0) {
        h_e[ty * NHEAD + (t >> 6)] = v;
        atomicMax(&hemax[t >> 6], enc_f32(v));
    }
}

__global__ __launch_bounds__(256) void k_setup(
        const void* __restrict__ Wv, const void* __restrict__ embv,
        const void* __restrict__ Wev, const void* __restrict__ aev,
        __hip_bfloat16* __restrict__ Wt, float* __restrict__ h_e,
        unsigned* __restrict__ hemax, const int* __restrict__ flag) {
    if (*flag) setup_body<float>((const float*)Wv, (const float*)embv,
                                 (const float*)Wev, (const float*)aev,
                                 Wt, h_e, hemax);
    else       setup_body<__hip_bfloat16>((const __hip_bfloat16*)Wv,
                                          (const __hip_bfloat16*)embv,
                                          (const __hip_bfloat16*)Wev,
                                          (const __hip_bfloat16*)aev,
                                          Wt, h_e, hemax);
}

// h = x @ W via mfma_f32_16x16x32_bf16. 4 waves/block; 12500 waves.
// Epilogue: hl/hr from in-register h (quarter-lane butterfly; col-half
// waves own disjoint heads -> plain stores).
template<typename T>
__device__ __forceinline__ void proj_body(const T* __restrict__ x,
        const __hip_bfloat16* __restrict__ Wt, __hip_bfloat16* __restrict__ h,
        float* __restrict__ hl, float* __restrict__ hr,
        const T* __restrict__ al, const T* __restrict__ ar) {
    int wid = threadIdx.x >> 6, lane = threadIdx.x & 63;
    int rg = blockIdx.x * 2 + (wid >> 1);
    if (rg >= 3125) return;                 // no barriers below: safe early-exit
    int toff = (wid & 1) * 4;               // col-half: t-tiles toff..toff+3
    int r0 = rg * 16;
    int r = lane & 15;
    int kb = (lane >> 4) * 8;
    const T* xrow = x + (size_t)(r0 + r) * IN_H;
    f32x4 z = {0.f, 0.f, 0.f, 0.f};
    f32x4 acc[4];
#pragma unroll
    for (int t = 0; t < 4; ++t) acc[t] = z;
#pragma unroll
    for (int kk = 0; kk < 8; ++kk) {
        int k0 = kk * 32 + kb;
        bf16x8v a;
        if constexpr (sizeof(T) == 4) {
            float4 lo = *(const float4*)(xrow + k0);
            float4 hi = *(const float4*)(xrow + k0 + 4);
            a[0] = f2bs(lo.x); a[1] = f2bs(lo.y); a[2] = f2bs(lo.z); a[3] = f2bs(lo.w);
            a[4] = f2bs(hi.x); a[5] = f2bs(hi.y); a[6] = f2bs(hi.z); a[7] = f2bs(hi.w);
        } else {
            a = *(const bf16x8v*)(xrow + k0);
        }
#pragma unroll
        for (int t = 0; t < 4; ++t) {
            bf16x8v b = *(const bf16x8v*)(Wt + ((toff + t) * 16 + r) * 256 + k0);
            acc[t] = __builtin_amdgcn_mfma_f32_16x16x32_bf16(a, b, acc[t], 0, 0, 0);
        }
    }
    float alc[4], arc[4];
#pragma unroll
    for (int t = 0; t < 4; ++t) {
        alc[t] = ldT(al + (toff + t) * 16 + r);
        arc[t] = ldT(ar + (toff + t) * 16 + r);
    }
    int ob = (lane >> 4) * 4;               // this quarter's row offset
    float pl[2][4] = {{0,0,0,0},{0,0,0,0}}, pr[2][4] = {{0,0,0,0},{0,0,0,0}};
#pragma unroll
    for (int t = 0; t < 4; ++t) {
        int col = (toff + t) * 16 + r;
#pragma unroll
        for (int g = 0; g < 4; ++g) {
            float v = acc[t][g];
            if (v != v) v = 0.f;            // reference: where(isnan(h), 0)
            h[(size_t)(r0 + ob + g) * 128 + col] = __float2bfloat16(v);
            pl[t >> 1][g] += alc[t] * v;
            pr[t >> 1][g] += arc[t] * v;
        }
    }
#pragma unroll
    for (int hh = 0; hh < 2; ++hh)
#pragma unroll
        for (int g = 0; g < 4; ++g) {
            float vl = pl[hh][g], vr = pr[hh][g];
#pragma unroll
            for (int off = 8; off; off >>= 1) {
                vl += __shfl_xor(vl, off);
                vr += __shfl_xor(vr, off);
            }
            if (r == 0) {
                int node = r0 + ob + g;
                hl[node * 4 + (toff >> 1) + hh] = vl;
                hr[node * 4 + (toff >> 1) + hh] = vr;
            }
        }
}

// Prologue: folded per-target edge counts into XCD-LOCAL counts8[blk&7]
// (R8: single-copy atomics cost ~50MB cross-XCD HBM traffic; R11: >1
// atomic/edge to hot lines is atomic-throughput-bound).
__global__ __launch_bounds__(256) void k_proj(const void* __restrict__ xv,
        const __hip_bfloat16* __restrict__ Wt, __hip_bfloat16* __restrict__ h,
        float* __restrict__ hl, float* __restrict__ hr,
        const void* __restrict__ alv, const void* __restrict__ arv,
        const int* __restrict__ edge, int* __restrict__ counts8,
        const int* __restrict__ flag) {
    {   // folded k_count, XCD-local copy (q matches k_build's mapping)
        int q = blockIdx.x & 7;
        int base = blockIdx.x * 1024;
        int lim = min(base + 1024, N_EDGES);
        int* cnt = counts8 + q * 50000;
        for (int i = base + threadIdx.x; i < lim; i += 256)
            atomicAdd(&cnt[edge[N_EDGES + i]], 1);
    }
    if (*flag) proj_body<float>((const float*)xv, Wt, h, hl, hr,
                                (const float*)alv, (const float*)arv);
    else       proj_body<__hip_bfloat16>((const __hip_bfloat16*)xv, Wt, h, hl,
                                         hr, (const __hip_bfloat16*)alv,
                                         (const __hip_bfloat16*)arv);
}

// ---- 2-phase multi-block scan (R9: 1-block scan was 502us) ----

// A: per-node totals over 8 copies + per-block sums. Also folds the hl
// per-head maxima (wave shfl-max + <=3136 atomicMax, measured-safe volume).
__global__ __launch_bounds__(256) void k_scanA(
        const int* __restrict__ counts8, int* __restrict__ node_tot,
        int* __restrict__ blk_sum, const float* __restrict__ hl,
        unsigned* __restrict__ hlmax) {
    int n = blockIdx.x * 256 + threadIdx.x;
    int tot = 0;
    const float NEG = -3.4e38f;
    float4 ml = {NEG, NEG, NEG, NEG};
    if (n < N_NODES) {
#pragma unroll
        for (int q = 0; q < 8; ++q) tot += counts8[q * 50000 + n];
        node_tot[n] = tot;
        ml = *(const float4*)(hl + n * 4);
    }
    __shared__ int red[256];
    red[threadIdx.x] = tot;
    __syncthreads();
    for (int off = 128; off; off >>= 1) {
        if (threadIdx.x < off) red[threadIdx.x] += red[threadIdx.x + off];
        __syncthreads();
    }
    if (threadIdx.x == 0) blk_sum[blockIdx.x] = red[0];
#pragma unroll
    for (int off = 32; off; off >>= 1) {
        ml.x = fmaxf(ml.x, __shfl_xor(ml.x, off));
        ml.y = fmaxf(ml.y, __shfl_xor(ml.y, off));
        ml.z = fmaxf(ml.z, __shfl_xor(ml.z, off));
        ml.w = fmaxf(ml.w, __shfl_xor(ml.w, off));
    }
    if ((threadIdx.x & 63) == 0) {
        atomicMax(&hlmax[0], enc_f32(ml.x)); atomicMax(&hlmax[1], enc_f32(ml.y));
        atomicMax(&hlmax[2], enc_f32(ml.z)); atomicMax(&hlmax[3], enc_f32(ml.w));
    }
}

// C: each block redundantly scans the 196 block sums in LDS (fused former
// k_scanB — removes a launch), then block-local exclusive scan of node_tot
// -> offsets[n] and per-copy bases off8[q][n]. 196 blocks.
__global__ __launch_bounds__(256) void k_scanC(
        const int* __restrict__ counts8, const int* __restrict__ node_tot,
        const int* __restrict__ blk_sum, int* __restrict__ offsets,
        int* __restrict__ off8) {
    __shared__ int bs[256];
    __shared__ int ps[256];
    int t = threadIdx.x;
    int bv = (t < 196) ? blk_sum[t] : 0;
    bs[t] = bv;
    __syncthreads();
    for (int off = 1; off < 256; off <<= 1) {
        int u = (t >= off) ? bs[t - off] : 0;
        __syncthreads();
        bs[t] += u;
        __syncthreads();
    }
    int blkBase = (blockIdx.x == 0) ? 0 : bs[blockIdx.x - 1];
    if (blockIdx.x == 195 && t == 0) offsets[N_NODES] = bs[195];
    int n = blockIdx.x * 256 + t;
    int v = (n < N_NODES) ? node_tot[n] : 0;
    ps[t] = v;
    __syncthreads();
    for (int off = 1; off < 256; off <<= 1) {
        int u = (t >= off) ? ps[t - off] : 0;
        __syncthreads();
        ps[t] += u;
        __syncthreads();
    }
    if (n < N_NODES) {
        int base = blkBase + ps[t] - v;
        offsets[n] = base;
#pragma unroll
        for (int q = 0; q < 8; ++q) {
            off8[q * 50000 + n] = base;
            base += counts8[q * 50000 + n];
        }
    }
}

// CSR build: per edge one 16B record {fp16 p0..p3, s, pad} + linear
// p_by_e[e] write. 1 edge/thread, 6250 blocks. q matches k_proj's
// counting copy: q = (blk>>2)&7. Per-target shift M_t,h =
// lrelu(hlmax_h + hr[t][h] + hemax_h) (R8-verified exact).
__global__ __launch_bounds__(256) void k_build(
        const int* __restrict__ edge, const int* __restrict__ off8,
        int* __restrict__ cursor8,
        const float* __restrict__ hl, const float* __restrict__ hr,
        const float* __restrict__ he,
        const unsigned* __restrict__ hlmax, const unsigned* __restrict__ hemax,
        int* __restrict__ rec, int* __restrict__ p_by_e) {
    float G0 = dec_f32(hlmax[0]) + dec_f32(hemax[0]);
    float G1 = dec_f32(hlmax[1]) + dec_f32(hemax[1]);
    float G2 = dec_f32(hlmax[2]) + dec_f32(hemax[2]);
    float G3 = dec_f32(hlmax[3]) + dec_f32(hemax[3]);
    int q = (blockIdx.x >> 2) & 7;
    const int* offq = off8 + q * 50000;
    int* curq = cursor8 + q * 50000;
    int e = blockIdx.x * 256 + threadIdx.x;   // 6250*256 == N_EDGES exactly
    int s = edge[e], t = edge[N_EDGES + e], ty = edge[2 * N_EDGES + e];
    int pos = offq[t] + atomicAdd(&curq[t], 1);
    float4 a = *(const float4*)(hl + s * 4);
    float4 b = *(const float4*)(hr + t * 4);
    float4 c = *(const float4*)(he + ty * 4);
    float p0 = __expf(lrelu(a.x + b.x + c.x) - lrelu(G0 + b.x));
    float p1 = __expf(lrelu(a.y + b.y + c.y) - lrelu(G1 + b.y));
    float p2 = __expf(lrelu(a.z + b.z + c.z) - lrelu(G2 + b.z));
    float p3 = __expf(lrelu(a.w + b.w + c.w) - lrelu(G3 + b.w));
    int4 w;
    w.x = (int)pack_h2(p0, p1);
    w.y = (int)pack_h2(p2, p3);
    w.z = s;
    w.w = 0;
    *(int4*)(rec + (size_t)pos * 4) = w;
    *(int2*)(p_by_e + (size_t)e * 2) = make_int2(w.x, w.y);  // linear
}

// one wave per node. pass1: lane-parallel denom over rec (coalesced, and
// rec stays L2-hot for pass 2); lane 0 stores denom[node] for k_attn.
// pass2: 4 edges/iter. Node order XCD-swizzled (bijective).
template<typename OUTT>
__device__ __forceinline__ void agg_body(
        const int* __restrict__ rec, const int* __restrict__ offsets,
        float* __restrict__ denom, const __hip_bfloat16* __restrict__ h,
        OUTT* __restrict__ out) {
    // bijective XCD swizzle over 12500 blocks: q=12500/8=1562, r=4
    int xcd = blockIdx.x & 7, idx = blockIdx.x >> 3;
    int nq = 1562, nr = 4;
    int sb = (xcd < nr) ? xcd * (nq + 1) + idx : nr * (nq + 1) + (xcd - nr) * nq + idx;
    int node = (sb << 2) + (threadIdx.x >> 6);
    if (node >= N_NODES) return;
    int lane = threadIdx.x & 63;
    int beg = offsets[node], end = offsets[node + 1];

    // pass 1: denominators
    float d0 = 0.f, d1 = 0.f, d2 = 0.f, d3 = 0.f;
    for (int j = beg + lane; j < end; j += 64) {
        int2 w = *(const int2*)(rec + (size_t)j * 4);
        float2 f01 = unpack_h2(w.x);
        float2 f23 = unpack_h2(w.y);
        d0 += f01.x; d1 += f01.y; d2 += f23.x; d3 += f23.y;
    }
#pragma unroll
    for (int off = 32; off; off >>= 1) {
        d0 += __shfl_xor(d0, off); d1 += __shfl_xor(d1, off);
        d2 += __shfl_xor(d2, off); d3 += __shfl_xor(d3, off);
    }
    if (lane == 0) *(float4*)(denom + node * 4) = make_float4(d0, d1, d2, d3);
    float inv0 = 1.f / (d0 + 1e-16f), inv1 = 1.f / (d1 + 1e-16f);
    float inv2 = 1.f / (d2 + 1e-16f), inv3 = 1.f / (d3 + 1e-16f);

    int sub = lane >> 4;          // edge slot within group of 4
    int l16 = lane & 15;          // dim group: flat dims l16*8 .. +8
    int hd  = l16 >> 2;           // head of my dims
    float invd = hd == 0 ? inv0 : hd == 1 ? inv1 : hd == 2 ? inv2 : inv3;

    float acc[8] = {0.f, 0.f, 0.f, 0.f, 0.f, 0.f, 0.f, 0.f};
    for (int jg = beg; jg < end; jg += 4) {
        int j = jg + sub;
        bool valid = j < end;
        int jc = valid ? j : end - 1;
        const int* rp = rec + (size_t)jc * 4;
        int pw = (hd < 2) ? rp[0] : rp[1];
        int s = rp[2];
        float2 f = unpack_h2(pw);
        float phd = (hd & 1) ? f.y : f.x;
        float wgt = valid ? phd * invd : 0.f;
        bf16x8v hv = *(const bf16x8v*)(h + (size_t)s * 128 + l16 * 8);
#pragma unroll
        for (int i = 0; i < 8; ++i) acc[i] += bs2f(hv[i]) * wgt;
    }
#pragma unroll
    for (int i = 0; i < 8; ++i) {
        acc[i] += __shfl_xor(acc[i], 16);
        acc[i] += __shfl_xor(acc[i], 32);
    }
    if (sub == 0) {
#pragma unroll
        for (int i = 0; i < 8; ++i)
            stT(&out[(size_t)node * 128 + l16 * 8 + i], acc[i]);
    }
}

__global__ __launch_bounds__(256) void k_agg(
        const int* __restrict__ rec, const int* __restrict__ offsets,
        float* __restrict__ denom, const __hip_bfloat16* __restrict__ h,
        void* __restrict__ outv, const int* __restrict__ flag) {
    if (*flag) agg_body<float>(rec, offsets, denom, h, (float*)outv);
    else       agg_body<__hip_bfloat16>(rec, offsets, denom, h,
                                        (__hip_bfloat16*)outv);
}

// attn output, fully linear: read p_by_e[e] + trg[e] sequentially,
// gather denom[t] (800KB, L2/L3-resident), write attn_out[e*4] coalesced.
template<typename OUTT>
__device__ __forceinline__ void attn_body(
        const int* __restrict__ p_by_e, const int* __restrict__ edge,
        const float* __restrict__ denom, OUTT* __restrict__ out) {
    int e = blockIdx.x * 256 + threadIdx.x;   // 6250*256 == N_EDGES
    int t = edge[N_EDGES + e];
    float4 d = *(const float4*)(denom + t * 4);
    int2 w = *(const int2*)(p_by_e + (size_t)e * 2);
    float2 f01 = unpack_h2(w.x);
    float2 f23 = unpack_h2(w.y);
    OUTT* attn_out = out + (size_t)N_NODES * 128;
    stT(&attn_out[(size_t)e * 4 + 0], f01.x / (d.x + 1e-16f));
    stT(&attn_out[(size_t)e * 4 + 1], f01.y / (d.y + 1e-16f));
    stT(&attn_out[(size_t)e * 4 + 2], f23.x / (d.z + 1e-16f));
    stT(&attn_out[(size_t)e * 4 + 3], f23.y / (d.w + 1e-16f));
}

__global__ __launch_bounds__(256) void k_attn(
        const int* __restrict__ p_by_e, const int* __restrict__ edge,
        const float* __restrict__ denom, void* __restrict__ outv,
        const int* __restrict__ flag) {
    if (*flag) attn_body<float>(p_by_e, edge, denom, (float*)outv);
    else       attn_body<__hip_bfloat16>(p_by_e, edge, denom,
                                         (__hip_bfloat16*)outv);
}

extern "C" void kernel_launch(void* const* d_in, const int* in_sizes, int n_in,
                              void* d_out, int out_size, void* d_ws, size_t ws_size,
                              hipStream_t stream) {
    const int* edge = (const int*)d_in[0];
    const void* x   = d_in[1];
    const void* emb = d_in[2];
    const void* W   = d_in[3];
    const void* We  = d_in[4];
    const void* al  = d_in[5];
    const void* ar  = d_in[6];
    const void* ae  = d_in[7];

    float* ws = (float*)d_ws;
    int* counts8    = (int*)ws;                        // 400000
    int* cursor8    = counts8 + 400000;                // 400000
    unsigned* hlmax = (unsigned*)(ws + 800000);        // 4
    unsigned* hemax = (unsigned*)(ws + 800008);        // 4
    int* flag       = (int*)ws + 800012;               // 1
    float* hl       = ws + 800064;                     // 200000
    float* hr       = ws + 1000064;                    // 200000
    int* offsets    = (int*)ws + 1200064;              // 50001
    int* off8       = (int*)ws + 1250112;              // 400000
    int* node_tot   = (int*)ws + 1650112;              // 50000
    int* blk_sum    = (int*)ws + 1700112;              // 256
    float* he       = ws + 1700624;                    // 32
    __hip_bfloat16* Wt = (__hip_bfloat16*)(ws + 1700656);  // 32768 bf16
    float* denom    = ws + 1717040;                    // 200000
    int* p_by_e     = (int*)ws + 1917040;              // 3200000
    int* rec        = (int*)ws + 5117040;              // 6400000 (16B/edge)
    __hip_bfloat16* h = (__hip_bfloat16*)(ws + 11517040);  // 6400000 bf16
    // total 14,717,040 words = 58.9 MB

    hipMemsetAsync(ws, 0, (size_t)800064 * 4, stream); // counts8+cursor8+maxima+flag

    k_detect<<<1, 64, 0, stream>>>((const unsigned*)x, flag);
    k_setup<<<1 + N_ET, 256, 0, stream>>>(W, emb, We, ae, Wt, he, hemax, flag);
    k_proj<<<1563, 256, 0, stream>>>(x, Wt, h, hl, hr, al, ar,
                                     edge, counts8, flag);
    k_scanA<<<196, 256, 0, stream>>>(counts8, node_tot, blk_sum, hl, hlmax);
    k_scanC<<<196, 256, 0, stream>>>(counts8, node_tot, blk_sum, offsets, off8);
    k_build<<<6250, 256, 0, stream>>>(edge, off8, cursor8, hl, hr, he,
                                      hlmax, hemax, rec, p_by_e);
    k_agg<<<12500, 256, 0, stream>>>(rec, offsets, denom, h, d_out, flag);
    k_attn<<<6250, 256, 0, stream>>>(p_by_e, edge, denom, d_out, flag);
}

// Round 15
// 426.380 us; speedup vs baseline: 1.7362x; 1.0181x over previous
//
#include <hip/hip_runtime.h>
#include <hip/hip_bf16.h>
#include <hip/hip_fp16.h>

#define N_NODES 50000
#define N_EDGES 1600000
#define IN_H 256
#define NHEAD 4
#define EDGE_H 64
#define N_ET 8

// ---- ws layout (word offsets), total 14,717,040 words = 58.9 MB ----
// counts8  int[8][50000]   @ 0         (zeroed; XCD-local copies)
// cursor8  int[8][50000]   @ 400000    (zeroed)
// hlmax    u32[4]          @ 800000    (zeroed)
// hemax    u32[4]          @ 800008
// flag     int[1]          @ 800012    (zero region ends @ 800064)
// hl       f32[200000]     @ 800064
// hr       f32[200000]     @ 1000064
// offsets  int[50001]      @ 1200064
// off8     int[8][50000]   @ 1250112
// node_tot int[50000]      @ 1650112
// blk_sum  int[256]        @ 1700112
// he       f32[32]         @ 1700624
// Wt       bf16[32768]     @ 1700656   (16384 words)
// denom    f32[200000]     @ 1717040   (written by k_agg pass 1)
// p_by_e   int[3200000]    @ 1917040   (8B/edge: fp16 p0..3, by edge id)
// rec      int[6400000]    @ 5117040   (16B/edge: fp16 p0..3, s, pad)
// h        bf16[6400000]   @ 11517040  (3200000 words)

typedef __attribute__((ext_vector_type(8))) short bf16x8v;
typedef __attribute__((ext_vector_type(4))) float f32x4;

__device__ __forceinline__ float ldT(const float* p) { return *p; }
__device__ __forceinline__ float ldT(const __hip_bfloat16* p) { return __bfloat162float(*p); }
__device__ __forceinline__ void stT(float* p, float v) { *p = v; }
__device__ __forceinline__ void stT(__hip_bfloat16* p, float v) { *p = __float2bfloat16(v); }

__device__ __forceinline__ short f2bs(float f) {
    __hip_bfloat16 b = __float2bfloat16(f);
    return (short)__builtin_bit_cast(unsigned short, b);
}
__device__ __forceinline__ float bs2f(short s) {
    return __uint_as_float(((unsigned)(unsigned short)s) << 16);
}

__device__ __forceinline__ unsigned enc_f32(float f) {
    unsigned u = __float_as_uint(f);
    return (u & 0x80000000u) ? ~u : (u | 0x80000000u);
}
__device__ __forceinline__ float dec_f32(unsigned u) {
    return __uint_as_float((u & 0x80000000u) ? (u & 0x7fffffffu) : ~u);
}
__device__ __forceinline__ float lrelu(float v) { return v > 0.f ? v : 0.2f * v; }

__device__ __forceinline__ unsigned pack_h2(float a, float b) {
    unsigned lo = (unsigned)__half_as_ushort(__float2half(a));
    unsigned hi = (unsigned)__half_as_ushort(__float2half(b));
    return lo | (hi << 16);
}
__device__ __forceinline__ float2 unpack_h2(int w) {
    __half2 h = __builtin_bit_cast(__half2, w);
    return __half22float2(h);
}

// dtype detector: fp32 N(0,1) words have exp-field in [64,160]; bf16-packed
// words don't. DEVICE-side sniffing only (in_sizes are element counts).
__global__ void k_detect(const unsigned* __restrict__ xw, int* __restrict__ flag) {
    int lane = threadIdx.x;   // 64 threads
    int cnt = 0;
    for (int i = lane; i < 1024; i += 64) {
        unsigned e = (xw[i] >> 23) & 255u;
        if (e >= 64u && e <= 160u) cnt++;
    }
    for (int off = 32; off; off >>= 1) cnt += __shfl_xor(cnt, off);
    if (lane == 0) *flag = (cnt > 512) ? 1 : 0;   // 1 = fp32, 0 = bf16
}

// b0: W[256][128] -> Wt[128][256] bf16. b1..8: edge-type projection.
template<typename T>
__device__ __forceinline__ void setup_body(const T* __restrict__ W,
        const T* __restrict__ emb, const T* __restrict__ We,
        const T* __restrict__ ae, __hip_bfloat16* __restrict__ Wt,
        float* __restrict__ h_e, unsigned* __restrict__ hemax) {
    if (blockIdx.x == 0) {
        for (int i = threadIdx.x; i < 128 * 256; i += 256) {
            int c = i >> 8, k = i & 255;
            Wt[i] = __float2bfloat16(ldT(W + k * 128 + c));
        }
        return;
    }
    int ty = blockIdx.x - 1;
    int t = threadIdx.x, lane = t & 63;
    float acc = 0.f;
    for (int k = 0; k < EDGE_H; ++k)
        acc += ldT(emb + ty * EDGE_H + k) * ldT(We + k * 256 + t);
    float v = ldT(ae + t) * acc;
    for (int off = 32; off; off >>= 1) v += __shfl_xor(v, off);
    if (lane == 0) {
        h_e[ty * NHEAD + (t >> 6)] = v;
        atomicMax(&hemax[t >> 6], enc_f32(v));
    }
}

__global__ __launch_bounds__(256) void k_setup(
        const void* __restrict__ Wv, const void* __restrict__ embv,
        const void* __restrict__ Wev, const void* __restrict__ aev,
        __hip_bfloat16* __restrict__ Wt, float* __restrict__ h_e,
        unsigned* __restrict__ hemax, const int* __restrict__ flag) {
    if (*flag) setup_body<float>((const float*)Wv, (const float*)embv,
                                 (const float*)Wev, (const float*)aev,
                                 Wt, h_e, hemax);
    else       setup_body<__hip_bfloat16>((const __hip_bfloat16*)Wv,
                                          (const __hip_bfloat16*)embv,
                                          (const __hip_bfloat16*)Wev,
                                          (const __hip_bfloat16*)aev,
                                          Wt, h_e, hemax);
}

// h = x @ W via mfma_f32_16x16x32_bf16.
// R14 post-mortem: 1563-block version was latency-bound (Occ 35%, all
// pipes idle). Now 3125 blocks x 4 waves = 12500 waves (~12/SIMD);
// each wave: 16 rows x 32 cols (2 t-tiles = ONE head), acc[2] (-8 VGPR).
// All 4 waves share the block's 16 x-rows (16KB -> L1-resident).
template<typename T>
__device__ __forceinline__ void proj_body(const T* __restrict__ x,
        const __hip_bfloat16* __restrict__ Wt, __hip_bfloat16* __restrict__ h,
        float* __restrict__ hl, float* __restrict__ hr,
        const T* __restrict__ al, const T* __restrict__ ar) {
    int wid = threadIdx.x >> 6, lane = threadIdx.x & 63;
    int rg = blockIdx.x;                    // 0..3124, rows rg*16..+16
    int toff = wid * 2;                     // t-tiles toff, toff+1 (head=wid)
    int r0 = rg * 16;
    int r = lane & 15;
    int kb = (lane >> 4) * 8;
    const T* xrow = x + (size_t)(r0 + r) * IN_H;
    f32x4 z = {0.f, 0.f, 0.f, 0.f};
    f32x4 acc[2];
    acc[0] = z; acc[1] = z;
#pragma unroll
    for (int kk = 0; kk < 8; ++kk) {
        int k0 = kk * 32 + kb;
        bf16x8v a;
        if constexpr (sizeof(T) == 4) {
            float4 lo = *(const float4*)(xrow + k0);
            float4 hi = *(const float4*)(xrow + k0 + 4);
            a[0] = f2bs(lo.x); a[1] = f2bs(lo.y); a[2] = f2bs(lo.z); a[3] = f2bs(lo.w);
            a[4] = f2bs(hi.x); a[5] = f2bs(hi.y); a[6] = f2bs(hi.z); a[7] = f2bs(hi.w);
        } else {
            a = *(const bf16x8v*)(xrow + k0);
        }
#pragma unroll
        for (int t = 0; t < 2; ++t) {
            bf16x8v b = *(const bf16x8v*)(Wt + ((toff + t) * 16 + r) * 256 + k0);
            acc[t] = __builtin_amdgcn_mfma_f32_16x16x32_bf16(a, b, acc[t], 0, 0, 0);
        }
    }
    float alc[2], arc[2];
#pragma unroll
    for (int t = 0; t < 2; ++t) {
        alc[t] = ldT(al + (toff + t) * 16 + r);
        arc[t] = ldT(ar + (toff + t) * 16 + r);
    }
    int ob = (lane >> 4) * 4;               // this quarter's row offset
    float pl[4] = {0, 0, 0, 0}, pr[4] = {0, 0, 0, 0};
#pragma unroll
    for (int t = 0; t < 2; ++t) {
        int col = (toff + t) * 16 + r;
#pragma unroll
        for (int g = 0; g < 4; ++g) {
            float v = acc[t][g];
            if (v != v) v = 0.f;            // reference: where(isnan(h), 0)
            h[(size_t)(r0 + ob + g) * 128 + col] = __float2bfloat16(v);
            pl[g] += alc[t] * v;
            pr[g] += arc[t] * v;
        }
    }
#pragma unroll
    for (int g = 0; g < 4; ++g) {
        float vl = pl[g], vr = pr[g];
#pragma unroll
        for (int off = 8; off; off >>= 1) {   // reduce over r within quarter
            vl += __shfl_xor(vl, off);
            vr += __shfl_xor(vr, off);
        }
        if (r == 0) {
            int node = r0 + ob + g;
            hl[node * 4 + wid] = vl;          // wave owns head 'wid'
            hr[node * 4 + wid] = vr;
        }
    }
}

// Prologue: folded per-target edge counts into XCD-LOCAL counts8[blk&7]
// (R8: single-copy atomics cost ~50MB cross-XCD HBM traffic; R11: >1
// atomic/edge to hot lines is atomic-throughput-bound).
__global__ __launch_bounds__(256) void k_proj(const void* __restrict__ xv,
        const __hip_bfloat16* __restrict__ Wt, __hip_bfloat16* __restrict__ h,
        float* __restrict__ hl, float* __restrict__ hr,
        const void* __restrict__ alv, const void* __restrict__ arv,
        const int* __restrict__ edge, int* __restrict__ counts8,
        const int* __restrict__ flag) {
    {   // folded k_count, XCD-local copy (q matches k_build's mapping)
        int q = blockIdx.x & 7;
        int base = blockIdx.x * 512;
        int lim = min(base + 512, N_EDGES);
        int* cnt = counts8 + q * 50000;
        for (int i = base + threadIdx.x; i < lim; i += 256)
            atomicAdd(&cnt[edge[N_EDGES + i]], 1);
    }
    if (*flag) proj_body<float>((const float*)xv, Wt, h, hl, hr,
                                (const float*)alv, (const float*)arv);
    else       proj_body<__hip_bfloat16>((const __hip_bfloat16*)xv, Wt, h, hl,
                                         hr, (const __hip_bfloat16*)alv,
                                         (const __hip_bfloat16*)arv);
}

// ---- 2-phase multi-block scan (R9: 1-block scan was 502us) ----

// A: per-node totals over 8 copies + per-block sums. Also folds the hl
// per-head maxima (wave shfl-max + <=3136 atomicMax, measured-safe volume).
__global__ __launch_bounds__(256) void k_scanA(
        const int* __restrict__ counts8, int* __restrict__ node_tot,
        int* __restrict__ blk_sum, const float* __restrict__ hl,
        unsigned* __restrict__ hlmax) {
    int n = blockIdx.x * 256 + threadIdx.x;
    int tot = 0;
    const float NEG = -3.4e38f;
    float4 ml = {NEG, NEG, NEG, NEG};
    if (n < N_NODES) {
#pragma unroll
        for (int q = 0; q < 8; ++q) tot += counts8[q * 50000 + n];
        node_tot[n] = tot;
        ml = *(const float4*)(hl + n * 4);
    }
    __shared__ int red[256];
    red[threadIdx.x] = tot;
    __syncthreads();
    for (int off = 128; off; off >>= 1) {
        if (threadIdx.x < off) red[threadIdx.x] += red[threadIdx.x + off];
        __syncthreads();
    }
    if (threadIdx.x == 0) blk_sum[blockIdx.x] = red[0];
#pragma unroll
    for (int off = 32; off; off >>= 1) {
        ml.x = fmaxf(ml.x, __shfl_xor(ml.x, off));
        ml.y = fmaxf(ml.y, __shfl_xor(ml.y, off));
        ml.z = fmaxf(ml.z, __shfl_xor(ml.z, off));
        ml.w = fmaxf(ml.w, __shfl_xor(ml.w, off));
    }
    if ((threadIdx.x & 63) == 0) {
        atomicMax(&hlmax[0], enc_f32(ml.x)); atomicMax(&hlmax[1], enc_f32(ml.y));
        atomicMax(&hlmax[2], enc_f32(ml.z)); atomicMax(&hlmax[3], enc_f32(ml.w));
    }
}

// C: each block redundantly scans the 196 block sums in LDS (fused former
// k_scanB), then block-local exclusive scan of node_tot -> offsets[n] and
// per-copy bases off8[q][n]. 196 blocks.
__global__ __launch_bounds__(256) void k_scanC(
        const int* __restrict__ counts8, const int* __restrict__ node_tot,
        const int* __restrict__ blk_sum, int* __restrict__ offsets,
        int* __restrict__ off8) {
    __shared__ int bs[256];
    __shared__ int ps[256];
    int t = threadIdx.x;
    int bv = (t < 196) ? blk_sum[t] : 0;
    bs[t] = bv;
    __syncthreads();
    for (int off = 1; off < 256; off <<= 1) {
        int u = (t >= off) ? bs[t - off] : 0;
        __syncthreads();
        bs[t] += u;
        __syncthreads();
    }
    int blkBase = (blockIdx.x == 0) ? 0 : bs[blockIdx.x - 1];
    if (blockIdx.x == 195 && t == 0) offsets[N_NODES] = bs[195];
    int n = blockIdx.x * 256 + t;
    int v = (n < N_NODES) ? node_tot[n] : 0;
    ps[t] = v;
    __syncthreads();
    for (int off = 1; off < 256; off <<= 1) {
        int u = (t >= off) ? ps[t - off] : 0;
        __syncthreads();
        ps[t] += u;
        __syncthreads();
    }
    if (n < N_NODES) {
        int base = blkBase + ps[t] - v;
        offsets[n] = base;
#pragma unroll
        for (int q = 0; q < 8; ++q) {
            off8[q * 50000 + n] = base;
            base += counts8[q * 50000 + n];
        }
    }
}

// CSR build: per edge one 16B record {fp16 p0..p3, s, pad} + linear
// p_by_e[e] write. 1 edge/thread, 6250 blocks. q matches k_proj's
// counting copy: proj block b = e/512 uses q=b&7; this block covers
// e = blk*256.. so q = (blk>>1)&7. Per-target shift M_t,h =
// lrelu(hlmax_h + hr[t][h] + hemax_h) (R8-verified exact).
__global__ __launch_bounds__(256) void k_build(
        const int* __restrict__ edge, const int* __restrict__ off8,
        int* __restrict__ cursor8,
        const float* __restrict__ hl, const float* __restrict__ hr,
        const float* __restrict__ he,
        const unsigned* __restrict__ hlmax, const unsigned* __restrict__ hemax,
        int* __restrict__ rec, int* __restrict__ p_by_e) {
    float G0 = dec_f32(hlmax[0]) + dec_f32(hemax[0]);
    float G1 = dec_f32(hlmax[1]) + dec_f32(hemax[1]);
    float G2 = dec_f32(hlmax[2]) + dec_f32(hemax[2]);
    float G3 = dec_f32(hlmax[3]) + dec_f32(hemax[3]);
    int q = (blockIdx.x >> 1) & 7;
    const int* offq = off8 + q * 50000;
    int* curq = cursor8 + q * 50000;
    int e = blockIdx.x * 256 + threadIdx.x;   // 6250*256 == N_EDGES exactly
    int s = edge[e], t = edge[N_EDGES + e], ty = edge[2 * N_EDGES + e];
    int pos = offq[t] + atomicAdd(&curq[t], 1);
    float4 a = *(const float4*)(hl + s * 4);
    float4 b = *(const float4*)(hr + t * 4);
    float4 c = *(const float4*)(he + ty * 4);
    float p0 = __expf(lrelu(a.x + b.x + c.x) - lrelu(G0 + b.x));
    float p1 = __expf(lrelu(a.y + b.y + c.y) - lrelu(G1 + b.y));
    float p2 = __expf(lrelu(a.z + b.z + c.z) - lrelu(G2 + b.z));
    float p3 = __expf(lrelu(a.w + b.w + c.w) - lrelu(G3 + b.w));
    int4 w;
    w.x = (int)pack_h2(p0, p1);
    w.y = (int)pack_h2(p2, p3);
    w.z = s;
    w.w = 0;
    *(int4*)(rec + (size_t)pos * 4) = w;
    *(int2*)(p_by_e + (size_t)e * 2) = make_int2(w.x, w.y);  // linear
}

// one wave per node. pass1: lane-parallel denom over rec (coalesced, and
// rec stays L2-hot for pass 2); lane 0 stores denom[node] for k_attn.
// pass2: 4 edges/iter. Node order XCD-swizzled (bijective).
template<typename OUTT>
__device__ __forceinline__ void agg_body(
        const int* __restrict__ rec, const int* __restrict__ offsets,
        float* __restrict__ denom, const __hip_bfloat16* __restrict__ h,
        OUTT* __restrict__ out) {
    // bijective XCD swizzle over 12500 blocks: q=12500/8=1562, r=4
    int xcd = blockIdx.x & 7, idx = blockIdx.x >> 3;
    int nq = 1562, nr = 4;
    int sb = (xcd < nr) ? xcd * (nq + 1) + idx : nr * (nq + 1) + (xcd - nr) * nq + idx;
    int node = (sb << 2) + (threadIdx.x >> 6);
    if (node >= N_NODES) return;
    int lane = threadIdx.x & 63;
    int beg = offsets[node], end = offsets[node + 1];

    // pass 1: denominators
    float d0 = 0.f, d1 = 0.f, d2 = 0.f, d3 = 0.f;
    for (int j = beg + lane; j < end; j += 64) {
        int2 w = *(const int2*)(rec + (size_t)j * 4);
        float2 f01 = unpack_h2(w.x);
        float2 f23 = unpack_h2(w.y);
        d0 += f01.x; d1 += f01.y; d2 += f23.x; d3 += f23.y;
    }
#pragma unroll
    for (int off = 32; off; off >>= 1) {
        d0 += __shfl_xor(d0, off); d1 += __shfl_xor(d1, off);
        d2 += __shfl_xor(d2, off); d3 += __shfl_xor(d3, off);
    }
    if (lane == 0) *(float4*)(denom + node * 4) = make_float4(d0, d1, d2, d3);
    float inv0 = 1.f / (d0 + 1e-16f), inv1 = 1.f / (d1 + 1e-16f);
    float inv2 = 1.f / (d2 + 1e-16f), inv3 = 1.f / (d3 + 1e-16f);

    int sub = lane >> 4;          // edge slot within group of 4
    int l16 = lane & 15;          // dim group: flat dims l16*8 .. +8
    int hd  = l16 >> 2;           // head of my dims
    float invd = hd == 0 ? inv0 : hd == 1 ? inv1 : hd == 2 ? inv2 : inv3;

    float acc[8] = {0.f, 0.f, 0.f, 0.f, 0.f, 0.f, 0.f, 0.f};
    for (int jg = beg; jg < end; jg += 4) {
        int j = jg + sub;
        bool valid = j < end;
        int jc = valid ? j : end - 1;
        const int* rp = rec + (size_t)jc * 4;
        int pw = (hd < 2) ? rp[0] : rp[1];
        int s = rp[2];
        float2 f = unpack_h2(pw);
        float phd = (hd & 1) ? f.y : f.x;
        float wgt = valid ? phd * invd : 0.f;
        bf16x8v hv = *(const bf16x8v*)(h + (size_t)s * 128 + l16 * 8);
#pragma unroll
        for (int i = 0; i < 8; ++i) acc[i] += bs2f(hv[i]) * wgt;
    }
#pragma unroll
    for (int i = 0; i < 8; ++i) {
        acc[i] += __shfl_xor(acc[i], 16);
        acc[i] += __shfl_xor(acc[i], 32);
    }
    if (sub == 0) {
#pragma unroll
        for (int i = 0; i < 8; ++i)
            stT(&out[(size_t)node * 128 + l16 * 8 + i], acc[i]);
    }
}

__global__ __launch_bounds__(256) void k_agg(
        const int* __restrict__ rec, const int* __restrict__ offsets,
        float* __restrict__ denom, const __hip_bfloat16* __restrict__ h,
        void* __restrict__ outv, const int* __restrict__ flag) {
    if (*flag) agg_body<float>(rec, offsets, denom, h, (float*)outv);
    else       agg_body<__hip_bfloat16>(rec, offsets, denom, h,
                                        (__hip_bfloat16*)outv);
}

// attn output, fully linear: read p_by_e[e] + trg[e] sequentially,
// gather denom[t] (800KB, L2/L3-resident), write attn_out[e*4] coalesced.
template<typename OUTT>
__device__ __forceinline__ void attn_body(
        const int* __restrict__ p_by_e, const int* __restrict__ edge,
        const float* __restrict__ denom, OUTT* __restrict__ out) {
    int e = blockIdx.x * 256 + threadIdx.x;   // 6250*256 == N_EDGES
    int t = edge[N_EDGES + e];
    float4 d = *(const float4*)(denom + t * 4);
    int2 w = *(const int2*)(p_by_e + (size_t)e * 2);
    float2 f01 = unpack_h2(w.x);
    float2 f23 = unpack_h2(w.y);
    OUTT* attn_out = out + (size_t)N_NODES * 128;
    stT(&attn_out[(size_t)e * 4 + 0], f01.x / (d.x + 1e-16f));
    stT(&attn_out[(size_t)e * 4 + 1], f01.y / (d.y + 1e-16f));
    stT(&attn_out[(size_t)e * 4 + 2], f23.x / (d.z + 1e-16f));
    stT(&attn_out[(size_t)e * 4 + 3], f23.y / (d.w + 1e-16f));
}

__global__ __launch_bounds__(256) void k_attn(
        const int* __restrict__ p_by_e, const int* __restrict__ edge,
        const float* __restrict__ denom, void* __restrict__ outv,
        const int* __restrict__ flag) {
    if (*flag) attn_body<float>(p_by_e, edge, denom, (float*)outv);
    else       attn_body<__hip_bfloat16>(p_by_e, edge, denom,
                                         (__hip_bfloat16*)outv);
}

extern "C" void kernel_launch(void* const* d_in, const int* in_sizes, int n_in,
                              void* d_out, int out_size, void* d_ws, size_t ws_size,
                              hipStream_t stream) {
    const int* edge = (const int*)d_in[0];
    const void* x   = d_in[1];
    const void* emb = d_in[2];
    const void* W   = d_in[3];
    const void* We  = d_in[4];
    const void* al  = d_in[5];
    const void* ar  = d_in[6];
    const void* ae  = d_in[7];

    float* ws = (float*)d_ws;
    int* counts8    = (int*)ws;                        // 400000
    int* cursor8    = counts8 + 400000;                // 400000
    unsigned* hlmax = (unsigned*)(ws + 800000);        // 4
    unsigned* hemax = (unsigned*)(ws + 800008);        // 4
    int* flag       = (int*)ws + 800012;               // 1
    float* hl       = ws + 800064;                     // 200000
    float* hr       = ws + 1000064;                    // 200000
    int* offsets    = (int*)ws + 1200064;              // 50001
    int* off8       = (int*)ws + 1250112;              // 400000
    int* node_tot   = (int*)ws + 1650112;              // 50000
    int* blk_sum    = (int*)ws + 1700112;              // 256
    float* he       = ws + 1700624;                    // 32
    __hip_bfloat16* Wt = (__hip_bfloat16*)(ws + 1700656);  // 32768 bf16
    float* denom    = ws + 1717040;                    // 200000
    int* p_by_e     = (int*)ws + 1917040;              // 3200000
    int* rec        = (int*)ws + 5117040;              // 6400000 (16B/edge)
    __hip_bfloat16* h = (__hip_bfloat16*)(ws + 11517040);  // 6400000 bf16
    // total 14,717,040 words = 58.9 MB

    hipMemsetAsync(ws, 0, (size_t)800064 * 4, stream); // counts8+cursor8+maxima+flag

    k_detect<<<1, 64, 0, stream>>>((const unsigned*)x, flag);
    k_setup<<<1 + N_ET, 256, 0, stream>>>(W, emb, We, ae, Wt, he, hemax, flag);
    k_proj<<<3125, 256, 0, stream>>>(x, Wt, h, hl, hr, al, ar,
                                     edge, counts8, flag);
    k_scanA<<<196, 256, 0, stream>>>(counts8, node_tot, blk_sum, hl, hlmax);
    k_scanC<<<196, 256, 0, stream>>>(counts8, node_tot, blk_sum, offsets, off8);
    k_build<<<6250, 256, 0, stream>>>(edge, off8, cursor8, hl, hr, he,
                                      hlmax, hemax, rec, p_by_e);
    k_agg<<<12500, 256, 0, stream>>>(rec, offsets, denom, h, d_out, flag);
    k_attn<<<6250, 256, 0, stream>>>(p_by_e, edge, denom, d_out, flag);
}